// Round 8
// baseline (264.923 us; speedup 1.0000x reference)
//
#include <hip/hip_runtime.h>
#include <hip/hip_cooperative_groups.h>
#include <stdint.h>
#include <math.h>

namespace cg = cooperative_groups;

typedef __attribute__((ext_vector_type(4))) float f32x4;
typedef __attribute__((ext_vector_type(8))) short bfrag;   // 8 bf16 (4 VGPRs)
typedef __attribute__((ext_vector_type(4))) float cfrag;   // MFMA accum

#define SM_BYTES 53248

// ---------------- threefry2x32 (JAX-exact) ----------------
__device__ __forceinline__ uint32_t rotl32_(uint32_t v, int d) {
    return (v << d) | (v >> (32 - d));
}

__device__ uint32_t jax_random_bits(uint32_t key_lo, uint32_t flat) {
    uint32_t a, b;
    bool first;
    if (flat < 65536u) { a = flat; b = flat + 65536u; first = true; }
    else               { a = flat - 65536u; b = flat; first = false; }
    uint32_t ks0 = 0u, ks1 = key_lo, ks2 = 0u ^ key_lo ^ 0x1BD11BDAu;
    uint32_t x0 = a + ks0, x1 = b + ks1;
    const int r0[4] = {13, 15, 26, 6};
    const int r1[4] = {17, 29, 16, 24};
#define TF_R4(RS) { for (int rr = 0; rr < 4; ++rr) { x0 += x1; x1 = rotl32_(x1, RS[rr]); x1 ^= x0; } }
    TF_R4(r0); x0 += ks1; x1 += ks2 + 1u;
    TF_R4(r1); x0 += ks2; x1 += ks0 + 2u;
    TF_R4(r0); x0 += ks0; x1 += ks1 + 3u;
    TF_R4(r1); x0 += ks1; x1 += ks2 + 4u;
    TF_R4(r0); x0 += ks2; x1 += ks0 + 5u;
#undef TF_R4
    return first ? x0 : x1;
}

__device__ float jax_gumbel(uint32_t key_lo, uint32_t flat) {
    uint32_t bits = jax_random_bits(key_lo, flat);
    uint32_t v = (bits >> 9) | 0x3F800000u;
    float u = __uint_as_float(v) - 1.0f;
    u = u + 1e-10f;
    u = fmaxf(1e-10f, u);
    return -logf(-logf(u));
}

__device__ __forceinline__ uint32_t f2bf(float f) {   // RNE f32->bf16 bits
    uint32_t u = __float_as_uint(f);
    return (u + 0x7FFFu + ((u >> 16) & 1u)) >> 16;
}

struct KParams {
    const float *obs, *hs, *cs, *w_obs, *b_obs, *w_ih, *b_ih, *w_hh, *b_hh;
    const float *w_me, *b_me, *w_md, *b_md;
    const float *s1w1, *s1b1, *s1w2, *s1b2, *s1w3, *s1b3;
    const float *s2w1, *s2b1, *s2w2, *s2b2, *s2w3, *s2b3;
    const float *g1w, *g1ai, *g1aj, *g1b, *g2w, *g2ai, *g2aj, *g2b;
    const float *wv, *bv, *wa, *ba;
    float *h_new, *c_new, *value, *action;
    float *comm, *A1, *B1, *A2, *B2, *adj1, *adj2, *h1, *ci1, *cj1;
    float *comm2, *h2, *ci2, *cj2;
};

// ---------------- stage: fused obs-proj + LSTM (b: 32 row-groups x 8 col-groups) ----------------
__device__ __forceinline__ void lstm_stage(const KParams& p, char* SM, int b, int t) {
    float* o_l = (float*)SM;              // [8][128]  (4096 B)
    float* h_l = (float*)(SM + 4096);     // [8][256]  (8192 B)
    float* x_l = (float*)(SM + 12288);    // [8][256]  (8192 B)
    float* red = (float*)(SM + 20480);    // [8192] f32 (32768 B) -> ends 53248
    int r0 = (b & 31) * 8, c0 = (b >> 5) * 32;
    ((f32x4*)o_l)[t] = ((const f32x4*)(p.obs + r0 * 128))[t];
    ((f32x4*)h_l)[t] = ((const f32x4*)(p.hs + r0 * 256))[t];
    ((f32x4*)h_l)[t + 256] = ((const f32x4*)(p.hs + r0 * 256))[t + 256];
    __syncthreads();
    {   // obs proj
        int ks = t >> 6, q = t & 63;
        f32x4 acc[8];
#pragma unroll
        for (int r = 0; r < 8; ++r) acc[r] = (f32x4){0.f, 0.f, 0.f, 0.f};
#pragma unroll
        for (int k = ks * 32; k < ks * 32 + 32; ++k) {
            f32x4 w = *(const f32x4*)(p.w_obs + k * 256 + q * 4);
#pragma unroll
            for (int r = 0; r < 8; ++r) {
                float xv = o_l[r * 128 + k];
                acc[r].x += xv * w.x; acc[r].y += xv * w.y;
                acc[r].z += xv * w.z; acc[r].w += xv * w.w;
            }
        }
#pragma unroll
        for (int r = 0; r < 8; ++r)
            *(f32x4*)&red[(ks * 8 + r) * 256 + q * 4] = acc[r];
    }
    __syncthreads();
#pragma unroll
    for (int rep = 0; rep < 8; ++rep) {
        int o = t + rep * 256;
        int r = o >> 8, c = o & 255;
        float s = p.b_obs[c];
#pragma unroll
        for (int k2 = 0; k2 < 4; ++k2) s += red[(k2 * 8 + r) * 256 + c];
        x_l[r * 256 + c] = s;
    }
    __syncthreads();
    {   // gates
        int ks = t >> 5, cg2 = t & 31;
        int g2 = cg2 >> 3, qd = cg2 & 7;
        int col = g2 * 256 + c0 + qd * 4;
        const float* W = (ks < 4) ? p.w_ih : p.w_hh;
        const float* xl = (ks < 4) ? x_l : h_l;
        int kb = (ks & 3) * 64;
        f32x4 acc[8];
#pragma unroll
        for (int r = 0; r < 8; ++r) acc[r] = (f32x4){0.f, 0.f, 0.f, 0.f};
#pragma unroll
        for (int kk = 0; kk < 64; ++kk) {
            int k = kb + kk;
            f32x4 w = *(const f32x4*)(W + k * 1024 + col);
#pragma unroll
            for (int r = 0; r < 8; ++r) {
                float xv = xl[r * 256 + k];
                acc[r].x += xv * w.x; acc[r].y += xv * w.y;
                acc[r].z += xv * w.z; acc[r].w += xv * w.w;
            }
        }
        __syncthreads();
#pragma unroll
        for (int r = 0; r < 8; ++r)
            *(f32x4*)&red[(ks * 8 + r) * 128 + cg2 * 4] = acc[r];
    }
    __syncthreads();
    {
        int r = t >> 5, hc = t & 31;
        int gc = c0 + hc;
        float gate[4];
#pragma unroll
        for (int g2 = 0; g2 < 4; ++g2) {
            float s = p.b_ih[g2 * 256 + gc] + p.b_hh[g2 * 256 + gc];
#pragma unroll
            for (int ks = 0; ks < 8; ++ks) s += red[(ks * 8 + r) * 128 + g2 * 32 + hc];
            gate[g2] = s;
        }
        float ig = 1.f / (1.f + expf(-gate[0]));
        float fg = 1.f / (1.f + expf(-gate[1]));
        float gg = tanhf(gate[2]);
        float og = 1.f / (1.f + expf(-gate[3]));
        float cn = fg * p.cs[(r0 + r) * 256 + gc] + ig * gg;
        float hn = og * tanhf(cn);
        p.h_new[(r0 + r) * 256 + gc] = hn;
        p.c_new[(r0 + r) * 256 + gc] = cn;
    }
}

// ---------------- 8-row x 64-col GEMM tile core ----------------
template<int K>
__device__ __forceinline__ void gemm_core(const float* __restrict__ X, int xs, int r0,
                                          const float* __restrict__ W, int wsb,
                                          const float* __restrict__ bias,
                                          float* __restrict__ Y, int ys, int t,
                                          float* xr, float* red) {
    constexpr int KQ = K / 4;
#pragma unroll
    for (int q = t; q < 2 * K; q += 256) {
        int r = q / KQ, c = q % KQ;
        ((f32x4*)xr)[r * KQ + c] = ((const f32x4*)(X + (r0 + r) * xs))[c];
    }
    __syncthreads();
    constexpr int KP = K / 16;
    int qd = t & 15, ks = t >> 4;
    f32x4 acc[8];
#pragma unroll
    for (int r = 0; r < 8; ++r) acc[r] = (f32x4){0.f, 0.f, 0.f, 0.f};
#pragma unroll
    for (int k = ks * KP; k < ks * KP + KP; ++k) {
        f32x4 w = *(const f32x4*)(W + k * wsb + qd * 4);
#pragma unroll
        for (int r = 0; r < 8; ++r) {
            float xv = xr[r * K + k];
            acc[r].x += xv * w.x; acc[r].y += xv * w.y;
            acc[r].z += xv * w.z; acc[r].w += xv * w.w;
        }
    }
#pragma unroll
    for (int r = 0; r < 8; ++r)
        *(f32x4*)&red[(ks * 8 + r) * 64 + qd * 4] = acc[r];
    __syncthreads();
#pragma unroll
    for (int rep = 0; rep < 2; ++rep) {
        int o = t + rep * 256;
        int r = o >> 6, c = o & 63;
        float s = bias ? bias[c] : 0.f;
#pragma unroll
        for (int ks2 = 0; ks2 < 16; ++ks2) s += red[(ks2 * 8 + r) * 64 + c];
        Y[(r0 + r) * ys + c] = s;
    }
}

// ---------------- stage: comm = h_new @ w_me + b_me (blocks 0..127) ----------------
__device__ __forceinline__ void comm_stage(const KParams& p, char* SM, int b, int t) {
    if (b >= 128) return;
    float* xr = (float*)SM;
    float* red = (float*)(SM + 16384);
    int cb = (b >> 5) * 64;
    gemm_core<256>(p.h_new, 256, (b & 31) * 8, p.w_me + cb, 256, p.b_me + cb,
                   p.comm + cb, 256, t, xr, red);
}

// ---------------- stage: h1 + A/B projections (2 passes per block) ----------------
__device__ __forceinline__ void mgemm_stage(const KParams& p, char* SM, int b, int t) {
    float* xr = (float*)SM;
    float* red = (float*)(SM + 16384);
    int bx = b & 31;
#pragma unroll
    for (int pass = 0; pass < 2; ++pass) {
        int y = (b >> 5) + pass * 8;
        const float* W; int wsb; const float* bias; float* Y; int ys;
        if (y < 8) {
            W = p.g1w + y * 64; wsb = 512; bias = nullptr; Y = p.h1 + y * 64; ys = 512;
        } else {
            int idx = y - 8;
            int sel = idx >> 2, part = (idx >> 1) & 1, half = idx & 1;
            W = (sel ? p.s2w1 : p.s1w1) + part * (256 * 128) + half * 64; wsb = 128;
            bias = part ? nullptr : ((sel ? p.s2b1 : p.s1b1) + half * 64);
            float* tgt = sel ? (part ? p.B2 : p.A2) : (part ? p.B1 : p.A1);
            Y = tgt + half * 64; ys = 128;
        }
        gemm_core<256>(p.comm, 256, bx * 8, W, wsb, bias, Y, ys, t, xr, red);
        __syncthreads();
    }
}

// ---------------- scheduler body (agent i, scheduler s), z1 processed in 2 j-halves ----------------
__device__ __forceinline__ void sched_body(const KParams& p, char* SM, int i, int s, int t) {
    char* z1z2 = SM;                          // 32768: z1 bf16 [128][128] swz | z2 f32 [128][36]
    char* w2l  = SM + 32768;                  // 8192: w2^T bf16 [32][128] swz
    float* a_l  = (float*)(SM + 40960);       // 512
    float* b2_l = (float*)(SM + 41472);       // 128
    float* w3_l = (float*)(SM + 41600);       // 256
    float* b3_l = (float*)(SM + 41856);       // 8
    const float* A  = s ? p.A2 : p.A1;
    const float* B  = s ? p.B2 : p.B1;
    const float* w2 = s ? p.s2w2 : p.s1w2;
    const float* b2 = s ? p.s2b2 : p.s1b2;
    const float* w3 = s ? p.s2w3 : p.s1w3;
    const float* b3 = s ? p.s2b3 : p.s1b3;
    float* adj = s ? p.adj2 : p.adj1;
    uint32_t key_lo = (uint32_t)(s + 1);

    if (t < 32) ((f32x4*)a_l)[t] = ((const f32x4*)(A + i * 128))[t];
    if (t < 32) b2_l[t] = b2[t];
    if (t < 64) w3_l[t] = w3[t];
    if (t < 2)  b3_l[t] = b3[t];
    {   // w2 [128][32] -> bf16 transposed [c][k], swizzled
        int c = t & 31, kq = t >> 5;
        uint32_t* dst = (uint32_t*)w2l;
#pragma unroll
        for (int e = 0; e < 8; ++e) {
            int k = kq * 16 + e * 2;
            uint32_t word = f2bf(w2[k * 32 + c]) | (f2bf(w2[(k + 1) * 32 + c]) << 16);
            int byte = (c * 256 + k * 2) ^ ((c & 7) << 4);
            dst[byte >> 2] = word;
        }
    }
    __syncthreads();
    // w2 B-fragments (invariant across j-halves)
    int w = t >> 6, l = t & 63;
    bfrag bf[2][4];
#pragma unroll
    for (int ct = 0; ct < 2; ++ct)
#pragma unroll
        for (int ks = 0; ks < 4; ++ks) {
            int col = ct * 16 + (l & 15);
            int k = ks * 32 + (l >> 4) * 8;
            int byte = (col * 256 + k * 2) ^ ((col & 7) << 4);
            bf[ct][ks] = *(bfrag*)(w2l + byte);
        }
#pragma unroll
    for (int jh = 0; jh < 2; ++jh) {
        int jb = jh * 128;
        // z1 = relu(A[i] + B[j]) for 128 local rows -> bf16 LDS, swizzled
#pragma unroll
        for (int rep = 0; rep < 2; ++rep) {
            int jl = (t >> 2) + rep * 64;
            int kq = t & 3;
            const f32x4* bp = (const f32x4*)(B + (jb + jl) * 128 + kq * 32);
            uint32_t words[16];
#pragma unroll
            for (int q = 0; q < 8; ++q) {
                f32x4 bv = bp[q];
                int k = kq * 32 + q * 4;
                float z0 = fmaxf(a_l[k] + bv.x, 0.f);
                float z1v = fmaxf(a_l[k + 1] + bv.y, 0.f);
                float z2v = fmaxf(a_l[k + 2] + bv.z, 0.f);
                float z3v = fmaxf(a_l[k + 3] + bv.w, 0.f);
                words[q * 2]     = f2bf(z0) | (f2bf(z1v) << 16);
                words[q * 2 + 1] = f2bf(z2v) | (f2bf(z3v) << 16);
            }
#pragma unroll
            for (int w4 = 0; w4 < 4; ++w4) {
                int byte = (jl * 256 + kq * 64 + w4 * 16) ^ ((jl & 7) << 4);
                *(uint4*)(z1z2 + byte) = make_uint4(words[w4 * 4], words[w4 * 4 + 1],
                                                    words[w4 * 4 + 2], words[w4 * 4 + 3]);
            }
        }
        __syncthreads();
        // MFMA: z2[128 jl][32 c] = z1 @ w2 — wave w: row-tiles (w*2+rt)*16
        cfrag acc[2][2];
        cfrag zz = {0.f, 0.f, 0.f, 0.f};
#pragma unroll
        for (int rt = 0; rt < 2; ++rt) { acc[rt][0] = zz; acc[rt][1] = zz; }
#pragma unroll
        for (int rt = 0; rt < 2; ++rt) {
            int jl = (w * 2 + rt) * 16 + (l & 15);
#pragma unroll
            for (int ks = 0; ks < 4; ++ks) {
                int byte = (jl * 256 + (ks * 32 + (l >> 4) * 8) * 2) ^ ((jl & 7) << 4);
                bfrag af = *(bfrag*)(z1z2 + byte);
                acc[rt][0] = __builtin_amdgcn_mfma_f32_16x16x32_bf16(af, bf[0][ks], acc[rt][0], 0, 0, 0);
                acc[rt][1] = __builtin_amdgcn_mfma_f32_16x16x32_bf16(af, bf[1][ks], acc[rt][1], 0, 0, 0);
            }
        }
        __syncthreads();                      // all z1 reads done; reuse region as z2
        float* z2 = (float*)z1z2;             // [128][36] padded
#pragma unroll
        for (int rt = 0; rt < 2; ++rt)
#pragma unroll
            for (int ct = 0; ct < 2; ++ct)
#pragma unroll
                for (int r = 0; r < 4; ++r) {
                    int jl = (w * 2 + rt) * 16 + (l >> 4) * 4 + r;
                    int c = ct * 16 + (l & 15);
                    z2[jl * 36 + c] = acc[rt][ct][r];
                }
        __syncthreads();
        if (t < 128) {                        // epilogue: one local j per thread
            int j = jb + t;
            float p0 = 0.f, p1 = 0.f;
#pragma unroll
            for (int c = 0; c < 32; ++c) {
                float zv = fmaxf(z2[t * 36 + c] + b2_l[c], 0.f);
                p0 += zv * w3_l[2 * c];
                p1 += zv * w3_l[2 * c + 1];
            }
            float l0 = p0 + b3_l[0], l1 = p1 + b3_l[1];
            uint32_t flat = (uint32_t)(i * 256 + j) * 2u;
            float g0 = jax_gumbel(key_lo, flat);
            float g1 = jax_gumbel(key_lo, flat + 1u);
            adj[i * 256 + j] = (l1 + g1 > l0 + g0) ? 1.0f : 0.0f;
        }
        __syncthreads();                      // z2 reads done before next half's z1 build
    }
}

// ---------------- stage: both schedulers + GAT1 att coefs ----------------
__device__ __forceinline__ void sched_attc_stage(const KParams& p, char* SM, int b, int t) {
#pragma unroll
    for (int s = 0; s < 2; ++s) {
        __syncthreads();
        sched_body(p, SM, b, s, t);
    }
    // attc1: needs only h1 row b (ready since last grid sync)
    int h = t >> 6, lane = t & 63, n = b;
    float pi = 0.f, pj = 0.f;
#pragma unroll
    for (int f = lane; f < 128; f += 64) {
        float v = p.h1[n * 512 + h * 128 + f];
        pi += v * p.g1ai[h * 128 + f];
        pj += v * p.g1aj[h * 128 + f];
    }
#pragma unroll
    for (int off = 32; off; off >>= 1) {
        pi += __shfl_xor(pi, off);
        pj += __shfl_xor(pj, off);
    }
    if (lane == 0) { p.ci1[n * 4 + h] = pi; p.cj1[n * 4 + h] = pj; }
}

// ---------------- stage: GAT1 (2 rows, 256-col slice per block) ----------------
__device__ __forceinline__ void gat1_stage(const KParams& p, char* SM, int b, int t) {
    float* att = (float*)SM;                  // [2][4][256]
    float* red = (float*)(SM + 8192);         // [4][2][256]
    int i0 = (b & 127) * 2, cb = (b >> 7) * 256;
#pragma unroll
    for (int r = 0; r < 2; ++r) {
        int i = i0 + r;
        float adjv = (t == i) ? 1.f : p.adj1[i * 256 + t];
#pragma unroll
        for (int h = 0; h < 4; ++h) {
            float e = p.ci1[i * 4 + h] + p.cj1[t * 4 + h];
            e = e >= 0.f ? e : 0.2f * e;
            att[(r * 4 + h) * 256 + t] = adjv > 0.f ? e : -INFINITY;
        }
    }
    __syncthreads();
    {
        int wv = t >> 6, lane = t & 63;
        for (int pp = wv; pp < 8; pp += 4) {
            int r = pp >> 2, h = pp & 3;
            float* ar = att + (r * 4 + h) * 256;
            float m = -INFINITY;
            for (int j = lane; j < 256; j += 64) m = fmaxf(m, ar[j]);
            for (int off = 32; off; off >>= 1) m = fmaxf(m, __shfl_xor(m, off));
            float vals[4], sm = 0.f;
#pragma unroll
            for (int q = 0; q < 4; ++q) {
                float v = expf(ar[lane + 64 * q] - m);
                vals[q] = v; sm += v;
            }
            for (int off = 32; off; off >>= 1) sm += __shfl_xor(sm, off);
            float inv = 1.f / sm;
#pragma unroll
            for (int q = 0; q < 4; ++q) ar[lane + 64 * q] = vals[q] * inv;
        }
    }
    __syncthreads();
    {
        int q = t & 63, js = t >> 6;
        int c = cb + q * 4;
        int h = c >> 7;
        f32x4 a0 = {0.f, 0.f, 0.f, 0.f}, a1 = a0;
        const float* ar0 = att + (0 * 4 + h) * 256;
        const float* ar1 = att + (1 * 4 + h) * 256;
#pragma unroll
        for (int j = js * 64; j < js * 64 + 64; ++j) {
            f32x4 hv = *(const f32x4*)(p.h1 + j * 512 + c);
            float v0 = ar0[j], v1 = ar1[j];
            a0.x += v0 * hv.x; a0.y += v0 * hv.y; a0.z += v0 * hv.z; a0.w += v0 * hv.w;
            a1.x += v1 * hv.x; a1.y += v1 * hv.y; a1.z += v1 * hv.z; a1.w += v1 * hv.w;
        }
        *(f32x4*)&red[(js * 2 + 0) * 256 + q * 4] = a0;
        *(f32x4*)&red[(js * 2 + 1) * 256 + q * 4] = a1;
    }
    __syncthreads();
#pragma unroll
    for (int rep = 0; rep < 2; ++rep) {
        int o = t + rep * 256;
        int r = o >> 8, c = o & 255;
        float s = red[(0 * 2 + r) * 256 + c] + red[(1 * 2 + r) * 256 + c]
                + red[(2 * 2 + r) * 256 + c] + red[(3 * 2 + r) * 256 + c] + p.g1b[cb + c];
        p.comm2[(i0 + r) * 512 + cb + c] = s > 0.f ? s : expm1f(s);
    }
}

// ---------------- stage: h2 = comm2 @ g2_w (blocks 0..127) ----------------
__device__ __forceinline__ void gemm512_stage(const KParams& p, char* SM, int b, int t) {
    if (b >= 128) return;
    float* xr = (float*)SM;
    float* red = (float*)(SM + 16384);
    int cb = (b >> 5) * 64;
    gemm_core<512>(p.comm2, 512, (b & 31) * 8, p.g2w + cb, 256, nullptr,
                   p.h2 + cb, 256, t, xr, red);
}

// ---------------- stage: GAT2 att coefs ----------------
__device__ __forceinline__ void attc2_stage(const KParams& p, int b, int t) {
    int w = t >> 6, lane = t & 63, n = b;
    if (w != 0) return;
    float pi = 0.f, pj = 0.f;
#pragma unroll
    for (int f = lane; f < 256; f += 64) {
        float v = p.h2[n * 256 + f];
        pi += v * p.g2ai[f];
        pj += v * p.g2aj[f];
    }
#pragma unroll
    for (int off = 32; off; off >>= 1) {
        pi += __shfl_xor(pi, off);
        pj += __shfl_xor(pj, off);
    }
    if (lane == 0) { p.ci2[n] = pi; p.cj2[n] = pj; }
}

// ---------------- stage: GAT2 + decode + heads ----------------
__device__ __forceinline__ void final_stage(const KParams& p, char* SM, int b, int t) {
    float* att   = (float*)SM;                // 256
    float* buf   = (float*)(SM + 1024);       // [4][256]
    float* out2  = (float*)(SM + 5120);       // 256
    float* comm3 = (float*)(SM + 6144);       // 256
    float* hrow  = (float*)(SM + 7168);       // 256
    float* hred  = (float*)(SM + 8192);       // [4][16]
    float* vred  = (float*)(SM + 8448);       // [4]
    int i = b;
    hrow[t] = p.h_new[i * 256 + t];
    {
        float adjv = (t == i) ? 1.f : p.adj2[i * 256 + t];
        float e = p.ci2[i] + p.cj2[t];
        e = e >= 0.f ? e : 0.2f * e;
        att[t] = adjv > 0.f ? e : -INFINITY;
    }
    __syncthreads();
    {
        int lane = t & 63;
        float m = -INFINITY;
        for (int j = lane; j < 256; j += 64) m = fmaxf(m, att[j]);
        for (int off = 32; off; off >>= 1) m = fmaxf(m, __shfl_xor(m, off));
        float sm = 0.f;
        for (int j = lane; j < 256; j += 64) sm += expf(att[j] - m);
        for (int off = 32; off; off >>= 1) sm += __shfl_xor(sm, off);
        float inv = 1.f / sm;
        float myval = expf(att[t] - m) * inv;
        __syncthreads();
        att[t] = myval;
    }
    __syncthreads();
    {   // out2 = att @ h2 (+ g2_b)
        int q = t & 63, js = t >> 6;
        f32x4 acc = {0.f, 0.f, 0.f, 0.f};
#pragma unroll
        for (int j = js * 64; j < js * 64 + 64; ++j) {
            f32x4 hv = *(const f32x4*)(p.h2 + j * 256 + q * 4);
            float av = att[j];
            acc.x += av * hv.x; acc.y += av * hv.y; acc.z += av * hv.z; acc.w += av * hv.w;
        }
        *(f32x4*)&buf[js * 256 + q * 4] = acc;
    }
    __syncthreads();
    out2[t] = buf[t] + buf[256 + t] + buf[512 + t] + buf[768 + t] + p.g2b[t];
    __syncthreads();
    {   // comm3 = out2 @ w_md + b_md
        int q = t & 63, ks = t >> 6;
        f32x4 acc = {0.f, 0.f, 0.f, 0.f};
#pragma unroll
        for (int k = ks * 64; k < ks * 64 + 64; ++k) {
            f32x4 wv = *(const f32x4*)(p.w_md + k * 256 + q * 4);
            float xv = out2[k];
            acc.x += xv * wv.x; acc.y += xv * wv.y; acc.z += xv * wv.z; acc.w += xv * wv.w;
        }
        *(f32x4*)&buf[ks * 256 + q * 4] = acc;
    }
    __syncthreads();
    comm3[t] = buf[t] + buf[256 + t] + buf[512 + t] + buf[768 + t] + p.b_md[t];
    __syncthreads();
    int w = t >> 6, l = t & 63;
    {   // value
        float pv = hrow[t] * p.wv[t] + comm3[t] * p.wv[256 + t];
        for (int off = 32; off; off >>= 1) pv += __shfl_xor(pv, off);
        if (l == 0) vred[w] = pv;
    }
    {   // action: o = l&15 (10 used), kseg = w*4 + (l>>4)
        int o = l & 15;
        int kseg = w * 4 + (l >> 4);
        float acc = 0.f;
        if (o < 10) {
#pragma unroll
            for (int kk = 0; kk < 32; ++kk) {
                int k = kseg * 32 + kk;
                float x = (kseg < 8) ? hrow[k] : comm3[k - 256];
                acc += x * p.wa[k * 10 + o];
            }
        }
        acc += __shfl_xor(acc, 16);
        acc += __shfl_xor(acc, 32);
        if (l < 16) hred[w * 16 + l] = acc;
    }
    __syncthreads();
    if (t < 16) {
        int o = t;
        float logit = (o < 10)
            ? hred[o] + hred[16 + o] + hred[32 + o] + hred[48 + o] + p.ba[o]
            : -INFINITY;
        float m = logit;
        for (int off = 8; off; off >>= 1) m = fmaxf(m, __shfl_xor(m, off));
        float ex = (o < 10) ? expf(logit - m) : 0.f;
        float sm = ex;
        for (int off = 8; off; off >>= 1) sm += __shfl_xor(sm, off);
        if (o < 10) p.action[i * 10 + o] = logit - m - logf(sm);
        if (o == 0) p.value[i] = vred[0] + vred[1] + vred[2] + vred[3] + p.bv[0];
    }
}

// ---------------- single cooperative kernel ----------------
__global__ __launch_bounds__(256) void k_all(KParams p) {
    __shared__ __align__(16) char SM[SM_BYTES];
    cg::grid_group grid = cg::this_grid();
    int b = blockIdx.x, t = threadIdx.x;
    lstm_stage(p, SM, b, t);        grid.sync();
    comm_stage(p, SM, b, t);        grid.sync();
    mgemm_stage(p, SM, b, t);       grid.sync();
    sched_attc_stage(p, SM, b, t);  grid.sync();
    gat1_stage(p, SM, b, t);        grid.sync();
    gemm512_stage(p, SM, b, t);     grid.sync();
    attc2_stage(p, b, t);           grid.sync();
    final_stage(p, SM, b, t);
}

// ---------------- fallback: stage wrapper kernels ----------------
__global__ __launch_bounds__(256) void ks_lstm(KParams p) {
    __shared__ __align__(16) char SM[SM_BYTES];
    lstm_stage(p, SM, blockIdx.x, threadIdx.x);
}
__global__ __launch_bounds__(256) void ks_comm(KParams p) {
    __shared__ __align__(16) char SM[SM_BYTES];
    comm_stage(p, SM, blockIdx.x, threadIdx.x);
}
__global__ __launch_bounds__(256) void ks_mgemm(KParams p) {
    __shared__ __align__(16) char SM[SM_BYTES];
    mgemm_stage(p, SM, blockIdx.x, threadIdx.x);
}
__global__ __launch_bounds__(256) void ks_schedattc(KParams p) {
    __shared__ __align__(16) char SM[SM_BYTES];
    sched_attc_stage(p, SM, blockIdx.x, threadIdx.x);
}
__global__ __launch_bounds__(256) void ks_gat1(KParams p) {
    __shared__ __align__(16) char SM[SM_BYTES];
    gat1_stage(p, SM, blockIdx.x, threadIdx.x);
}
__global__ __launch_bounds__(256) void ks_gemm512(KParams p) {
    __shared__ __align__(16) char SM[SM_BYTES];
    gemm512_stage(p, SM, blockIdx.x, threadIdx.x);
}
__global__ __launch_bounds__(64) void ks_attc2(KParams p) {
    attc2_stage(p, blockIdx.x, threadIdx.x);
}
__global__ __launch_bounds__(256) void ks_final(KParams p) {
    __shared__ __align__(16) char SM[SM_BYTES];
    final_stage(p, SM, blockIdx.x, threadIdx.x);
}

extern "C" void kernel_launch(void* const* d_in, const int* in_sizes, int n_in,
                              void* d_out, int out_size, void* d_ws, size_t ws_size,
                              hipStream_t stream) {
    float* out = (float*)d_out;
    float* ws = (float*)d_ws;

    KParams p;
    p.obs   = (const float*)d_in[0];
    p.hs    = (const float*)d_in[1];
    p.cs    = (const float*)d_in[2];
    p.w_obs = (const float*)d_in[3];
    p.b_obs = (const float*)d_in[4];
    p.w_ih  = (const float*)d_in[5];
    p.b_ih  = (const float*)d_in[6];
    p.w_hh  = (const float*)d_in[7];
    p.b_hh  = (const float*)d_in[8];
    p.w_me  = (const float*)d_in[9];
    p.b_me  = (const float*)d_in[10];
    p.w_md  = (const float*)d_in[11];
    p.b_md  = (const float*)d_in[12];
    p.s1w1  = (const float*)d_in[13];
    p.s1b1  = (const float*)d_in[14];
    p.s1w2  = (const float*)d_in[15];
    p.s1b2  = (const float*)d_in[16];
    p.s1w3  = (const float*)d_in[17];
    p.s1b3  = (const float*)d_in[18];
    p.s2w1  = (const float*)d_in[19];
    p.s2b1  = (const float*)d_in[20];
    p.s2w2  = (const float*)d_in[21];
    p.s2b2  = (const float*)d_in[22];
    p.s2w3  = (const float*)d_in[23];
    p.s2b3  = (const float*)d_in[24];
    p.g1w   = (const float*)d_in[25];
    p.g1ai  = (const float*)d_in[26];
    p.g1aj  = (const float*)d_in[27];
    p.g1b   = (const float*)d_in[28];
    p.g2w   = (const float*)d_in[29];
    p.g2ai  = (const float*)d_in[30];
    p.g2aj  = (const float*)d_in[31];
    p.g2b   = (const float*)d_in[32];
    p.wv    = (const float*)d_in[33];
    p.bv    = (const float*)d_in[34];
    p.wa    = (const float*)d_in[35];
    p.ba    = (const float*)d_in[36];

    p.action = out;                // [1,256,10] = 2560
    p.value  = out + 2560;         // [256,1]
    p.h_new  = out + 2816;         // [256,256]
    p.c_new  = out + 68352;        // [256,256]

    p.comm  = ws;                  // 65536
    p.A1    = ws + 65536;          // 32768
    p.B1    = ws + 98304;          // 32768
    p.A2    = ws + 131072;         // 32768
    p.B2    = ws + 163840;         // 32768
    p.adj1  = ws + 196608;         // 65536
    p.adj2  = ws + 262144;         // 65536
    p.h1    = ws + 327680;         // 131072
    p.ci1   = ws + 458752;         // 1024
    p.cj1   = ws + 459776;         // 1024
    p.comm2 = ws + 460800;         // 131072
    p.h2    = ws + 591872;         // 65536
    p.ci2   = ws + 657408;         // 256
    p.cj2   = ws + 657664;         // 256

    void* args[] = { (void*)&p };
    hipError_t err = hipLaunchCooperativeKernel((const void*)k_all, dim3(256), dim3(256),
                                                args, 0, stream);
    if (err != hipSuccess) {
        // fallback: same stages as separate kernels (proven R6 structure)
        ks_lstm<<<256, 256, 0, stream>>>(p);
        ks_comm<<<128, 256, 0, stream>>>(p);
        ks_mgemm<<<256, 256, 0, stream>>>(p);
        ks_schedattc<<<256, 256, 0, stream>>>(p);
        ks_gat1<<<256, 256, 0, stream>>>(p);
        ks_gemm512<<<128, 256, 0, stream>>>(p);
        ks_attc2<<<256, 64, 0, stream>>>(p);
        ks_final<<<256, 256, 0, stream>>>(p);
    }
}

// Round 9
// 69.318 us; speedup vs baseline: 3.8218x; 3.8218x over previous
//
#include <hip/hip_runtime.h>
#include <stdint.h>
#include <math.h>

#define NA 256

typedef __attribute__((ext_vector_type(4))) float f32x4;
typedef __attribute__((ext_vector_type(8))) short bfrag;   // 8 bf16 (4 VGPRs)
typedef __attribute__((ext_vector_type(4))) float cfrag;   // MFMA accum

// ---------------- threefry2x32 (JAX-exact) ----------------
__device__ __forceinline__ uint32_t rotl32_(uint32_t v, int d) {
    return (v << d) | (v >> (32 - d));
}

__device__ uint32_t jax_random_bits(uint32_t key_lo, uint32_t flat) {
    uint32_t a, b;
    bool first;
    if (flat < 65536u) { a = flat; b = flat + 65536u; first = true; }
    else               { a = flat - 65536u; b = flat; first = false; }
    uint32_t ks0 = 0u, ks1 = key_lo, ks2 = 0u ^ key_lo ^ 0x1BD11BDAu;
    uint32_t x0 = a + ks0, x1 = b + ks1;
    const int r0[4] = {13, 15, 26, 6};
    const int r1[4] = {17, 29, 16, 24};
#define TF_R4(RS) { for (int rr = 0; rr < 4; ++rr) { x0 += x1; x1 = rotl32_(x1, RS[rr]); x1 ^= x0; } }
    TF_R4(r0); x0 += ks1; x1 += ks2 + 1u;
    TF_R4(r1); x0 += ks2; x1 += ks0 + 2u;
    TF_R4(r0); x0 += ks0; x1 += ks1 + 3u;
    TF_R4(r1); x0 += ks1; x1 += ks2 + 4u;
    TF_R4(r0); x0 += ks2; x1 += ks0 + 5u;
#undef TF_R4
    return first ? x0 : x1;
}

__device__ float jax_gumbel(uint32_t key_lo, uint32_t flat) {
    uint32_t bits = jax_random_bits(key_lo, flat);
    uint32_t v = (bits >> 9) | 0x3F800000u;
    float u = __uint_as_float(v) - 1.0f;
    u = u + 1e-10f;
    u = fmaxf(1e-10f, u);
    return -logf(-logf(u));
}

__device__ __forceinline__ uint32_t f2bf(float f) {   // RNE f32->bf16 bits
    uint32_t u = __float_as_uint(f);
    return (u + 0x7FFFu + ((u >> 16) & 1u)) >> 16;
}

// ---------------- fused obs-proj + LSTM cell ----------------
// grid (32, 8): 8 rows, 32 hid-cols (=128 gate-cols) per block
// block (0,0) also zeroes the ci/cj atomic accumulators for this call
__global__ __launch_bounds__(256) void k_lstm(
        const float* __restrict__ obs, const float* __restrict__ hs,
        const float* __restrict__ cs,
        const float* __restrict__ w_obs, const float* __restrict__ b_obs,
        const float* __restrict__ w_ih, const float* __restrict__ b_ih,
        const float* __restrict__ w_hh, const float* __restrict__ b_hh,
        float* __restrict__ h_out, float* __restrict__ c_out,
        float* __restrict__ ci1, float* __restrict__ cj1,
        float* __restrict__ ci2, float* __restrict__ cj2) {
    __shared__ float o_l[8][128];
    __shared__ float h_l[8][256];
    __shared__ float x_l[8][256];
    __shared__ float red[8192];            // 32KB, reused by both phases
    int r0 = blockIdx.x * 8, c0 = blockIdx.y * 32, t = threadIdx.x;
    if (blockIdx.x == 0 && blockIdx.y == 0) {
        for (int idx = t; idx < 1024; idx += 256) { ci1[idx] = 0.f; cj1[idx] = 0.f; }
        ci2[t] = 0.f; cj2[t] = 0.f;
    }
    ((f32x4*)o_l)[t] = ((const f32x4*)(obs + r0 * 128))[t];
    ((f32x4*)h_l)[t] = ((const f32x4*)(hs + r0 * 256))[t];
    ((f32x4*)h_l)[t + 256] = ((const f32x4*)(hs + r0 * 256))[t + 256];
    __syncthreads();
    {   // obs proj
        int ks = t >> 6, q = t & 63;
        f32x4 acc[8];
#pragma unroll
        for (int r = 0; r < 8; ++r) acc[r] = (f32x4){0.f, 0.f, 0.f, 0.f};
#pragma unroll
        for (int k = ks * 32; k < ks * 32 + 32; ++k) {
            f32x4 w = *(const f32x4*)(w_obs + k * 256 + q * 4);
#pragma unroll
            for (int r = 0; r < 8; ++r) {
                float xv = o_l[r][k];
                acc[r].x += xv * w.x; acc[r].y += xv * w.y;
                acc[r].z += xv * w.z; acc[r].w += xv * w.w;
            }
        }
#pragma unroll
        for (int r = 0; r < 8; ++r)
            *(f32x4*)&red[(ks * 8 + r) * 256 + q * 4] = acc[r];
    }
    __syncthreads();
#pragma unroll
    for (int rep = 0; rep < 8; ++rep) {
        int o = t + rep * 256;
        int r = o >> 8, c = o & 255;
        float s = b_obs[c];
#pragma unroll
        for (int k2 = 0; k2 < 4; ++k2) s += red[(k2 * 8 + r) * 256 + c];
        x_l[r][c] = s;
    }
    __syncthreads();
    {   // gates
        int ks = t >> 5, cg = t & 31;
        int g = cg >> 3, qd = cg & 7;
        int col = g * 256 + c0 + qd * 4;
        const float* W = (ks < 4) ? w_ih : w_hh;
        const float* xl = (ks < 4) ? &x_l[0][0] : &h_l[0][0];
        int kb = (ks & 3) * 64;
        f32x4 acc[8];
#pragma unroll
        for (int r = 0; r < 8; ++r) acc[r] = (f32x4){0.f, 0.f, 0.f, 0.f};
#pragma unroll
        for (int kk = 0; kk < 64; ++kk) {
            int k = kb + kk;
            f32x4 w = *(const f32x4*)(W + k * 1024 + col);
#pragma unroll
            for (int r = 0; r < 8; ++r) {
                float xv = xl[r * 256 + k];
                acc[r].x += xv * w.x; acc[r].y += xv * w.y;
                acc[r].z += xv * w.z; acc[r].w += xv * w.w;
            }
        }
        __syncthreads();
#pragma unroll
        for (int r = 0; r < 8; ++r)
            *(f32x4*)&red[(ks * 8 + r) * 128 + cg * 4] = acc[r];
    }
    __syncthreads();
    {
        int r = t >> 5, hc = t & 31;
        int gc = c0 + hc;
        float gate[4];
#pragma unroll
        for (int g = 0; g < 4; ++g) {
            float s = b_ih[g * 256 + gc] + b_hh[g * 256 + gc];
#pragma unroll
            for (int ks = 0; ks < 8; ++ks) s += red[(ks * 8 + r) * 128 + g * 32 + hc];
            gate[g] = s;
        }
        float ig = 1.f / (1.f + expf(-gate[0]));
        float fg = 1.f / (1.f + expf(-gate[1]));
        float gg = tanhf(gate[2]);
        float og = 1.f / (1.f + expf(-gate[3]));
        float cn = fg * cs[(r0 + r) * 256 + gc] + ig * gg;
        float hn = og * tanhf(cn);
        h_out[(r0 + r) * 256 + gc] = hn;
        c_out[(r0 + r) * 256 + gc] = cn;
    }
}

// ---------------- generic 8-row x 64-col GEMM tile ----------------
template<int K>
__device__ __forceinline__ void gemm_core(const float* __restrict__ X, int xs, int r0,
                                          const float* __restrict__ W, int ws,
                                          const float* __restrict__ bias,
                                          float* __restrict__ Y, int ys, int t,
                                          float* xr, float* red) {
    constexpr int KQ = K / 4;
#pragma unroll
    for (int q = t; q < 2 * K; q += 256) {
        int r = q / KQ, c = q % KQ;
        ((f32x4*)xr)[r * KQ + c] = ((const f32x4*)(X + (r0 + r) * xs))[c];
    }
    __syncthreads();
    constexpr int KP = K / 16;
    int qd = t & 15, ks = t >> 4;
    f32x4 acc[8];
#pragma unroll
    for (int r = 0; r < 8; ++r) acc[r] = (f32x4){0.f, 0.f, 0.f, 0.f};
#pragma unroll
    for (int k = ks * KP; k < ks * KP + KP; ++k) {
        f32x4 w = *(const f32x4*)(W + k * ws + qd * 4);
#pragma unroll
        for (int r = 0; r < 8; ++r) {
            float xv = xr[r * K + k];
            acc[r].x += xv * w.x; acc[r].y += xv * w.y;
            acc[r].z += xv * w.z; acc[r].w += xv * w.w;
        }
    }
#pragma unroll
    for (int r = 0; r < 8; ++r)
        *(f32x4*)&red[(ks * 8 + r) * 64 + qd * 4] = acc[r];
    __syncthreads();
#pragma unroll
    for (int rep = 0; rep < 2; ++rep) {
        int o = t + rep * 256;
        int r = o >> 6, c = o & 63;
        float s = bias ? bias[c] : 0.f;
#pragma unroll
        for (int ks2 = 0; ks2 < 16; ++ks2) s += red[(ks2 * 8 + r) * 64 + c];
        Y[(r0 + r) * ys + c] = s;
    }
}

template<int K>
__global__ __launch_bounds__(256) void k_gemm(const float* __restrict__ X, int xs,
                                              const float* __restrict__ W, int ws,
                                              const float* __restrict__ bias,
                                              float* __restrict__ Y, int ys) {
    __shared__ float xr[8 * K];
    __shared__ float red[16 * 8 * 64];
    int cb = blockIdx.y * 64;
    gemm_core<K>(X, xs, blockIdx.x * 8, W + cb, ws, bias ? bias + cb : nullptr,
                 Y + cb, ys, threadIdx.x, xr, red);
}

// multi-target GEMM from comm, with fused GAT1 att-coef partials (atomics).
// grid (32, 16): y<8 -> h1 slices (+ci1/cj1); y>=8 -> A1,B1,A2,B2 halves
__global__ __launch_bounds__(256) void k_mgemm(const float* __restrict__ comm,
        const float* __restrict__ g1_w, const float* __restrict__ g1ai,
        const float* __restrict__ g1aj,
        const float* __restrict__ s1w1, const float* __restrict__ s1b1,
        const float* __restrict__ s2w1, const float* __restrict__ s2b1,
        float* __restrict__ h1, float* __restrict__ A1, float* __restrict__ B1,
        float* __restrict__ A2, float* __restrict__ B2,
        float* __restrict__ ci1, float* __restrict__ cj1) {
    __shared__ float xr[8 * 256];
    __shared__ float red[16 * 8 * 64];
    int y = blockIdx.y, t = threadIdx.x, r0 = blockIdx.x * 8;
    const float* W; int ws; const float* bias; float* Y; int ys;
    if (y < 8) {
        W = g1_w + y * 64; ws = 512; bias = nullptr; Y = h1 + y * 64; ys = 512;
    } else {
        int idx = y - 8;
        int sel = idx >> 2, part = (idx >> 1) & 1, half = idx & 1;
        W = (sel ? s2w1 : s1w1) + part * (256 * 128) + half * 64; ws = 128;
        bias = part ? nullptr : ((sel ? s2b1 : s1b1) + half * 64);
        float* tgt = sel ? (part ? B2 : A2) : (part ? B1 : A1);
        Y = tgt + half * 64; ys = 128;
    }
    // gemm body (K=256)
#pragma unroll
    for (int q = t; q < 512; q += 256) {
        int r = q >> 6, c = q & 63;
        ((f32x4*)xr)[r * 64 + c] = ((const f32x4*)(comm + (r0 + r) * 256))[c];
    }
    __syncthreads();
    int qd = t & 15, ks = t >> 4;
    f32x4 acc[8];
#pragma unroll
    for (int r = 0; r < 8; ++r) acc[r] = (f32x4){0.f, 0.f, 0.f, 0.f};
#pragma unroll
    for (int k = ks * 16; k < ks * 16 + 16; ++k) {
        f32x4 w = *(const f32x4*)(W + k * ws + qd * 4);
#pragma unroll
        for (int r = 0; r < 8; ++r) {
            float xv = xr[r * 256 + k];
            acc[r].x += xv * w.x; acc[r].y += xv * w.y;
            acc[r].z += xv * w.z; acc[r].w += xv * w.w;
        }
    }
#pragma unroll
    for (int r = 0; r < 8; ++r)
        *(f32x4*)&red[(ks * 8 + r) * 64 + qd * 4] = acc[r];
    __syncthreads();
#pragma unroll
    for (int rep = 0; rep < 2; ++rep) {
        int o = t + rep * 256;
        int r = o >> 6, c = o & 63;     // wave-uniform row; c == lane
        float s = bias ? bias[c] : 0.f;
#pragma unroll
        for (int ks2 = 0; ks2 < 16; ++ks2) s += red[(ks2 * 8 + r) * 64 + c];
        Y[(r0 + r) * ys + c] = s;
        if (y < 8) {                    // fused attc1 partial for this 64-col slice
            int h = y >> 1;
            int f = ((y & 1) << 6) + c;
            float pi = s * g1ai[h * 128 + f];
            float pj = s * g1aj[h * 128 + f];
#pragma unroll
            for (int off = 32; off; off >>= 1) {
                pi += __shfl_xor(pi, off);
                pj += __shfl_xor(pj, off);
            }
            if ((t & 63) == 0) {
                atomicAdd(&ci1[(r0 + r) * 4 + h], pi);
                atomicAdd(&cj1[(r0 + r) * 4 + h], pj);
            }
        }
    }
}

// ---------------- scheduler: z1(bf16,LDS) -> MFMA z2 -> logits -> gumbel argmax ----------------
// grid (256, 2): block = (agent i, scheduler s)
__global__ __launch_bounds__(256) void k_sched(
        const float* __restrict__ A1, const float* __restrict__ B1,
        const float* __restrict__ s1w2, const float* __restrict__ s1b2,
        const float* __restrict__ s1w3, const float* __restrict__ s1b3,
        const float* __restrict__ A2, const float* __restrict__ B2,
        const float* __restrict__ s2w2, const float* __restrict__ s2b2,
        const float* __restrict__ s2w3, const float* __restrict__ s2b3,
        float* __restrict__ adj1, float* __restrict__ adj2) {
    __shared__ __align__(16) char z1z2[65536];   // z1 bf16 [256][128] swz | z2 f32 [256][36]
    __shared__ __align__(16) char w2l[8192];     // w2^T bf16 [32][128] swz
    __shared__ float a_l[128];
    __shared__ float b2_l[32], w3_l[64], b3_l[2];
    int i = blockIdx.x, t = threadIdx.x, s = blockIdx.y;
    const float* A  = s ? A2 : A1;
    const float* B  = s ? B2 : B1;
    const float* w2 = s ? s2w2 : s1w2;
    const float* b2 = s ? s2b2 : s1b2;
    const float* w3 = s ? s2w3 : s1w3;
    const float* b3 = s ? s2b3 : s1b3;
    float* adj = s ? adj2 : adj1;
    uint32_t key_lo = (uint32_t)(s + 1);

    if (t < 32) ((f32x4*)a_l)[t] = ((const f32x4*)(A + i * 128))[t];
    if (t < 32) b2_l[t] = b2[t];
    if (t < 64) w3_l[t] = w3[t];
    if (t < 2)  b3_l[t] = b3[t];
    {   // w2 [128][32] -> bf16 transposed [c][k], swizzled
        int c = t & 31, kq = t >> 5;
        uint32_t* dst = (uint32_t*)w2l;
#pragma unroll
        for (int e = 0; e < 8; ++e) {
            int k = kq * 16 + e * 2;
            uint32_t word = f2bf(w2[k * 32 + c]) | (f2bf(w2[(k + 1) * 32 + c]) << 16);
            int byte = (c * 256 + k * 2) ^ ((c & 7) << 4);
            dst[byte >> 2] = word;
        }
    }
    __syncthreads();
    // z1 = relu(A[i] + B[j]) -> bf16 LDS, swizzled rows
#pragma unroll
    for (int rep = 0; rep < 4; ++rep) {
        int j = (t >> 2) + rep * 64;
        int kq = t & 3;
        const f32x4* bp = (const f32x4*)(B + j * 128 + kq * 32);
        uint32_t words[16];
#pragma unroll
        for (int q = 0; q < 8; ++q) {
            f32x4 bv = bp[q];
            int k = kq * 32 + q * 4;
            float z0 = fmaxf(a_l[k] + bv.x, 0.f);
            float z1v = fmaxf(a_l[k + 1] + bv.y, 0.f);
            float z2v = fmaxf(a_l[k + 2] + bv.z, 0.f);
            float z3v = fmaxf(a_l[k + 3] + bv.w, 0.f);
            words[q * 2]     = f2bf(z0) | (f2bf(z1v) << 16);
            words[q * 2 + 1] = f2bf(z2v) | (f2bf(z3v) << 16);
        }
#pragma unroll
        for (int w4 = 0; w4 < 4; ++w4) {
            int byte = (j * 256 + kq * 64 + w4 * 16) ^ ((j & 7) << 4);
            *(uint4*)(z1z2 + byte) = make_uint4(words[w4 * 4], words[w4 * 4 + 1],
                                                words[w4 * 4 + 2], words[w4 * 4 + 3]);
        }
    }
    __syncthreads();
    // MFMA: z2[256 j][32 c] = z1 @ w2
    int w = t >> 6, l = t & 63;
    bfrag bf[2][4];
#pragma unroll
    for (int ct = 0; ct < 2; ++ct)
#pragma unroll
        for (int ks = 0; ks < 4; ++ks) {
            int col = ct * 16 + (l & 15);
            int k = ks * 32 + (l >> 4) * 8;
            int byte = (col * 256 + k * 2) ^ ((col & 7) << 4);
            bf[ct][ks] = *(bfrag*)(w2l + byte);
        }
    cfrag acc[4][2];
    cfrag zz = {0.f, 0.f, 0.f, 0.f};
#pragma unroll
    for (int rt = 0; rt < 4; ++rt) { acc[rt][0] = zz; acc[rt][1] = zz; }
#pragma unroll
    for (int rt = 0; rt < 4; ++rt) {
        int j = (w * 4 + rt) * 16 + (l & 15);
#pragma unroll
        for (int ks = 0; ks < 4; ++ks) {
            int byte = (j * 256 + (ks * 32 + (l >> 4) * 8) * 2) ^ ((j & 7) << 4);
            bfrag af = *(bfrag*)(z1z2 + byte);
            acc[rt][0] = __builtin_amdgcn_mfma_f32_16x16x32_bf16(af, bf[0][ks], acc[rt][0], 0, 0, 0);
            acc[rt][1] = __builtin_amdgcn_mfma_f32_16x16x32_bf16(af, bf[1][ks], acc[rt][1], 0, 0, 0);
        }
    }
    __syncthreads();
    float* z2 = (float*)z1z2;                    // [256][36] padded
#pragma unroll
    for (int rt = 0; rt < 4; ++rt)
#pragma unroll
        for (int ct = 0; ct < 2; ++ct)
#pragma unroll
            for (int r = 0; r < 4; ++r) {
                int j = (w * 4 + rt) * 16 + (l >> 4) * 4 + r;
                int c = ct * 16 + (l & 15);
                z2[j * 36 + c] = acc[rt][ct][r];
            }
    __syncthreads();
    {   // epilogue: one j per thread
        int j = t;
        float p0 = 0.f, p1 = 0.f;
#pragma unroll
        for (int c = 0; c < 32; ++c) {
            float zv = fmaxf(z2[j * 36 + c] + b2_l[c], 0.f);
            p0 += zv * w3_l[2 * c];
            p1 += zv * w3_l[2 * c + 1];
        }
        float l0 = p0 + b3_l[0], l1 = p1 + b3_l[1];
        uint32_t flat = (uint32_t)(i * 256 + j) * 2u;
        float g0 = jax_gumbel(key_lo, flat);
        float g1 = jax_gumbel(key_lo, flat + 1u);
        adj[i * 256 + j] = (l1 + g1 > l0 + g0) ? 1.0f : 0.0f;
    }
}

// ---------------- GAT1: grid (128, 2) — 2 rows, 256-col slice ----------------
__global__ __launch_bounds__(256) void k_gat1(const float* __restrict__ H,
        const float* __restrict__ adj, const float* __restrict__ ci,
        const float* __restrict__ cj, const float* __restrict__ bias,
        float* __restrict__ out) {
    __shared__ float att[2][4][256];
    __shared__ float red[4][2][256];
    int i0 = blockIdx.x * 2, cb = blockIdx.y * 256, t = threadIdx.x;
#pragma unroll
    for (int r = 0; r < 2; ++r) {
        int i = i0 + r;
        float adjv = (t == i) ? 1.f : adj[i * 256 + t];
#pragma unroll
        for (int h = 0; h < 4; ++h) {
            float e = ci[i * 4 + h] + cj[t * 4 + h];
            e = e >= 0.f ? e : 0.2f * e;
            att[r][h][t] = adjv > 0.f ? e : -INFINITY;
        }
    }
    __syncthreads();
    {
        int wv = t >> 6, lane = t & 63;
        for (int p = wv; p < 8; p += 4) {
            int r = p >> 2, h = p & 3;
            float* ar = att[r][h];
            float m = -INFINITY;
            for (int j = lane; j < 256; j += 64) m = fmaxf(m, ar[j]);
            for (int off = 32; off; off >>= 1) m = fmaxf(m, __shfl_xor(m, off));
            float vals[4], sm = 0.f;
#pragma unroll
            for (int q = 0; q < 4; ++q) {
                float v = expf(ar[lane + 64 * q] - m);
                vals[q] = v; sm += v;
            }
            for (int off = 32; off; off >>= 1) sm += __shfl_xor(sm, off);
            float inv = 1.f / sm;
#pragma unroll
            for (int q = 0; q < 4; ++q) ar[lane + 64 * q] = vals[q] * inv;
        }
    }
    __syncthreads();
    {
        int q = t & 63, js = t >> 6;
        int c = cb + q * 4;
        int h = c >> 7;
        f32x4 a0 = {0.f, 0.f, 0.f, 0.f}, a1 = a0;
        const float* ar0 = att[0][h];
        const float* ar1 = att[1][h];
#pragma unroll
        for (int j = js * 64; j < js * 64 + 64; ++j) {
            f32x4 hv = *(const f32x4*)(H + j * 512 + c);
            float v0 = ar0[j], v1 = ar1[j];
            a0.x += v0 * hv.x; a0.y += v0 * hv.y; a0.z += v0 * hv.z; a0.w += v0 * hv.w;
            a1.x += v1 * hv.x; a1.y += v1 * hv.y; a1.z += v1 * hv.z; a1.w += v1 * hv.w;
        }
        *(f32x4*)&red[js][0][q * 4] = a0;
        *(f32x4*)&red[js][1][q * 4] = a1;
    }
    __syncthreads();
#pragma unroll
    for (int rep = 0; rep < 2; ++rep) {
        int o = t + rep * 256;
        int r = o >> 8, c = o & 255;
        float s = red[0][r][c] + red[1][r][c] + red[2][r][c] + red[3][r][c] + bias[cb + c];
        out[(i0 + r) * 512 + cb + c] = s > 0.f ? s : expm1f(s);
    }
}

// ---------------- h2 = comm2 @ g2_w, fused GAT2 att-coef partials ----------------
// grid (32, 4)
__global__ __launch_bounds__(256) void k_g2gemm(const float* __restrict__ comm2,
        const float* __restrict__ g2w, const float* __restrict__ g2ai,
        const float* __restrict__ g2aj, float* __restrict__ h2,
        float* __restrict__ ci2, float* __restrict__ cj2) {
    __shared__ float xr[8 * 512];
    __shared__ float red[16 * 8 * 64];
    int t = threadIdx.x, r0 = blockIdx.x * 8, cb = blockIdx.y * 64;
    const float* W = g2w + cb;
#pragma unroll
    for (int q = t; q < 1024; q += 256) {
        int r = q >> 7, c = q & 127;
        ((f32x4*)xr)[r * 128 + c] = ((const f32x4*)(comm2 + (r0 + r) * 512))[c];
    }
    __syncthreads();
    int qd = t & 15, ks = t >> 4;
    f32x4 acc[8];
#pragma unroll
    for (int r = 0; r < 8; ++r) acc[r] = (f32x4){0.f, 0.f, 0.f, 0.f};
#pragma unroll
    for (int k = ks * 32; k < ks * 32 + 32; ++k) {
        f32x4 w = *(const f32x4*)(W + k * 256 + qd * 4);
#pragma unroll
        for (int r = 0; r < 8; ++r) {
            float xv = xr[r * 512 + k];
            acc[r].x += xv * w.x; acc[r].y += xv * w.y;
            acc[r].z += xv * w.z; acc[r].w += xv * w.w;
        }
    }
#pragma unroll
    for (int r = 0; r < 8; ++r)
        *(f32x4*)&red[(ks * 8 + r) * 64 + qd * 4] = acc[r];
    __syncthreads();
#pragma unroll
    for (int rep = 0; rep < 2; ++rep) {
        int o = t + rep * 256;
        int r = o >> 6, c = o & 63;     // wave-uniform row; c == lane
        float s = 0.f;
#pragma unroll
        for (int ks2 = 0; ks2 < 16; ++ks2) s += red[(ks2 * 8 + r) * 64 + c];
        h2[(r0 + r) * 256 + cb + c] = s;
        // fused attc2 partial
        float pi = s * g2ai[cb + c];
        float pj = s * g2aj[cb + c];
#pragma unroll
        for (int off = 32; off; off >>= 1) {
            pi += __shfl_xor(pi, off);
            pj += __shfl_xor(pj, off);
        }
        if ((t & 63) == 0) {
            atomicAdd(&ci2[r0 + r], pi);
            atomicAdd(&cj2[r0 + r], pj);
        }
    }
}

// ---------------- final: GAT2 + message-decode + value/action heads ----------------
__global__ __launch_bounds__(256) void k_final(const float* __restrict__ H,
        const float* __restrict__ adj, const float* __restrict__ ci,
        const float* __restrict__ cj, const float* __restrict__ g2_b,
        const float* __restrict__ w_md, const float* __restrict__ b_md,
        const float* __restrict__ h_new,
        const float* __restrict__ w_v, const float* __restrict__ b_v,
        const float* __restrict__ w_a, const float* __restrict__ b_a,
        float* __restrict__ value, float* __restrict__ action) {
    __shared__ float att[256];
    __shared__ float buf[4][256];
    __shared__ float out2[256];
    __shared__ float comm3[256];
    __shared__ float hrow[256];
    __shared__ float hred[4][16];
    __shared__ float vred[4];
    int i = blockIdx.x, t = threadIdx.x;
    hrow[t] = h_new[i * 256 + t];
    {
        float adjv = (t == i) ? 1.f : adj[i * 256 + t];
        float e = ci[i] + cj[t];
        e = e >= 0.f ? e : 0.2f * e;
        att[t] = adjv > 0.f ? e : -INFINITY;
    }
    __syncthreads();
    {
        int lane = t & 63;
        float m = -INFINITY;
        for (int j = lane; j < 256; j += 64) m = fmaxf(m, att[j]);
        for (int off = 32; off; off >>= 1) m = fmaxf(m, __shfl_xor(m, off));
        float sm = 0.f;
        for (int j = lane; j < 256; j += 64) sm += expf(att[j] - m);
        for (int off = 32; off; off >>= 1) sm += __shfl_xor(sm, off);
        float inv = 1.f / sm;
        float myval = expf(att[t] - m) * inv;
        __syncthreads();
        att[t] = myval;
    }
    __syncthreads();
    {   // out2 = att @ H (+ g2_b)
        int q = t & 63, js = t >> 6;
        f32x4 acc = {0.f, 0.f, 0.f, 0.f};
#pragma unroll
        for (int j = js * 64; j < js * 64 + 64; ++j) {
            f32x4 hv = *(const f32x4*)(H + j * 256 + q * 4);
            float av = att[j];
            acc.x += av * hv.x; acc.y += av * hv.y; acc.z += av * hv.z; acc.w += av * hv.w;
        }
        *(f32x4*)&buf[js][q * 4] = acc;
    }
    __syncthreads();
    out2[t] = buf[0][t] + buf[1][t] + buf[2][t] + buf[3][t] + g2_b[t];
    __syncthreads();
    {   // comm3 = out2 @ w_md + b_md
        int q = t & 63, ks = t >> 6;
        f32x4 acc = {0.f, 0.f, 0.f, 0.f};
#pragma unroll
        for (int k = ks * 64; k < ks * 64 + 64; ++k) {
            f32x4 wv = *(const f32x4*)(w_md + k * 256 + q * 4);
            float xv = out2[k];
            acc.x += xv * wv.x; acc.y += xv * wv.y; acc.z += xv * wv.z; acc.w += xv * wv.w;
        }
        *(f32x4*)&buf[ks][q * 4] = acc;
    }
    __syncthreads();
    comm3[t] = buf[0][t] + buf[1][t] + buf[2][t] + buf[3][t] + b_md[t];
    __syncthreads();
    int w = t >> 6, l = t & 63;
    {   // value
        float p = hrow[t] * w_v[t] + comm3[t] * w_v[256 + t];
        for (int off = 32; off; off >>= 1) p += __shfl_xor(p, off);
        if (l == 0) vred[w] = p;
    }
    {   // action: o = l&15 (10 used), kseg = w*4 + (l>>4)
        int o = l & 15;
        int kseg = w * 4 + (l >> 4);
        float acc = 0.f;
        if (o < 10) {
#pragma unroll
            for (int kk = 0; kk < 32; ++kk) {
                int k = kseg * 32 + kk;
                float x = (kseg < 8) ? hrow[k] : comm3[k - 256];
                acc += x * w_a[k * 10 + o];
            }
        }
        acc += __shfl_xor(acc, 16);
        acc += __shfl_xor(acc, 32);
        if (l < 16) hred[w][l] = acc;
    }
    __syncthreads();
    if (t < 16) {
        int o = t;
        float logit = (o < 10)
            ? hred[0][o] + hred[1][o] + hred[2][o] + hred[3][o] + b_a[o]
            : -INFINITY;
        float m = logit;
        for (int off = 8; off; off >>= 1) m = fmaxf(m, __shfl_xor(m, off));
        float ex = (o < 10) ? expf(logit - m) : 0.f;
        float sm = ex;
        for (int off = 8; off; off >>= 1) sm += __shfl_xor(sm, off);
        if (o < 10) action[i * 10 + o] = logit - m - logf(sm);
        if (o == 0) value[i] = vred[0] + vred[1] + vred[2] + vred[3] + b_v[0];
    }
}

extern "C" void kernel_launch(void* const* d_in, const int* in_sizes, int n_in,
                              void* d_out, int out_size, void* d_ws, size_t ws_size,
                              hipStream_t stream) {
    const float* obs   = (const float*)d_in[0];
    const float* hs    = (const float*)d_in[1];
    const float* cs    = (const float*)d_in[2];
    const float* w_obs = (const float*)d_in[3];
    const float* b_obs = (const float*)d_in[4];
    const float* w_ih  = (const float*)d_in[5];
    const float* b_ih  = (const float*)d_in[6];
    const float* w_hh  = (const float*)d_in[7];
    const float* b_hh  = (const float*)d_in[8];
    const float* w_me  = (const float*)d_in[9];
    const float* b_me  = (const float*)d_in[10];
    const float* w_md  = (const float*)d_in[11];
    const float* b_md  = (const float*)d_in[12];
    const float* s1_w1 = (const float*)d_in[13];
    const float* s1_b1 = (const float*)d_in[14];
    const float* s1_w2 = (const float*)d_in[15];
    const float* s1_b2 = (const float*)d_in[16];
    const float* s1_w3 = (const float*)d_in[17];
    const float* s1_b3 = (const float*)d_in[18];
    const float* s2_w1 = (const float*)d_in[19];
    const float* s2_b1 = (const float*)d_in[20];
    const float* s2_w2 = (const float*)d_in[21];
    const float* s2_b2 = (const float*)d_in[22];
    const float* s2_w3 = (const float*)d_in[23];
    const float* s2_b3 = (const float*)d_in[24];
    const float* g1_w  = (const float*)d_in[25];
    const float* g1_ai = (const float*)d_in[26];
    const float* g1_aj = (const float*)d_in[27];
    const float* g1_b  = (const float*)d_in[28];
    const float* g2_w  = (const float*)d_in[29];
    const float* g2_ai = (const float*)d_in[30];
    const float* g2_aj = (const float*)d_in[31];
    const float* g2_b  = (const float*)d_in[32];
    const float* w_v   = (const float*)d_in[33];
    const float* b_v   = (const float*)d_in[34];
    const float* w_a   = (const float*)d_in[35];
    const float* b_a   = (const float*)d_in[36];

    float* out = (float*)d_out;
    float* action = out;               // [1,256,10] = 2560
    float* value  = out + 2560;        // [256,1]
    float* h_new  = out + 2816;        // [256,256]
    float* c_new  = out + 68352;       // [256,256]

    float* ws = (float*)d_ws;
    float* comm  = ws;                 // 65536
    float* A1    = ws + 65536;         // 32768
    float* B1    = ws + 98304;         // 32768
    float* A2    = ws + 131072;        // 32768
    float* B2    = ws + 163840;        // 32768
    float* adj1  = ws + 196608;        // 65536
    float* adj2  = ws + 262144;        // 65536
    float* h1    = ws + 327680;        // 131072
    float* ci1   = ws + 458752;        // 1024
    float* cj1   = ws + 459776;        // 1024
    float* comm2 = ws + 460800;        // 131072
    float* h2    = ws + 591872;        // 65536
    float* ci2   = ws + 657408;        // 256
    float* cj2   = ws + 657664;        // 256

    k_lstm<<<dim3(32, 8), 256, 0, stream>>>(obs, hs, cs, w_obs, b_obs,
                                            w_ih, b_ih, w_hh, b_hh, h_new, c_new,
                                            ci1, cj1, ci2, cj2);
    k_gemm<256><<<dim3(32, 4), 256, 0, stream>>>(h_new, 256, w_me, 256, b_me, comm, 256);
    k_mgemm<<<dim3(32, 16), 256, 0, stream>>>(comm, g1_w, g1_ai, g1_aj,
                                              s1_w1, s1_b1, s2_w1, s2_b1,
                                              h1, A1, B1, A2, B2, ci1, cj1);
    k_sched<<<dim3(256, 2), 256, 0, stream>>>(A1, B1, s1_w2, s1_b2, s1_w3, s1_b3,
                                              A2, B2, s2_w2, s2_b2, s2_w3, s2_b3,
                                              adj1, adj2);
    k_gat1<<<dim3(128, 2), 256, 0, stream>>>(h1, adj1, ci1, cj1, g1_b, comm2);
    k_g2gemm<<<dim3(32, 4), 256, 0, stream>>>(comm2, g2_w, g2_ai, g2_aj, h2, ci2, cj2);
    k_final<<<NA, 256, 0, stream>>>(h2, adj2, ci2, cj2, g2_b, w_md, b_md, h_new,
                                    w_v, b_v, w_a, b_a, value, action);
}

// Round 10
// 67.203 us; speedup vs baseline: 3.9421x; 1.0315x over previous
//
#include <hip/hip_runtime.h>
#include <stdint.h>
#include <math.h>

#define NA 256

typedef __attribute__((ext_vector_type(4))) float f32x4;
typedef __attribute__((ext_vector_type(8))) short bfrag;   // 8 bf16 (4 VGPRs)
typedef __attribute__((ext_vector_type(4))) float cfrag;   // MFMA accum

// ---------------- threefry2x32 (JAX-exact) ----------------
__device__ __forceinline__ uint32_t rotl32_(uint32_t v, int d) {
    return (v << d) | (v >> (32 - d));
}

__device__ uint32_t jax_random_bits(uint32_t key_lo, uint32_t flat) {
    uint32_t a, b;
    bool first;
    if (flat < 65536u) { a = flat; b = flat + 65536u; first = true; }
    else               { a = flat - 65536u; b = flat; first = false; }
    uint32_t ks0 = 0u, ks1 = key_lo, ks2 = 0u ^ key_lo ^ 0x1BD11BDAu;
    uint32_t x0 = a + ks0, x1 = b + ks1;
    const int r0[4] = {13, 15, 26, 6};
    const int r1[4] = {17, 29, 16, 24};
#define TF_R4(RS) { for (int rr = 0; rr < 4; ++rr) { x0 += x1; x1 = rotl32_(x1, RS[rr]); x1 ^= x0; } }
    TF_R4(r0); x0 += ks1; x1 += ks2 + 1u;
    TF_R4(r1); x0 += ks2; x1 += ks0 + 2u;
    TF_R4(r0); x0 += ks0; x1 += ks1 + 3u;
    TF_R4(r1); x0 += ks1; x1 += ks2 + 4u;
    TF_R4(r0); x0 += ks2; x1 += ks0 + 5u;
#undef TF_R4
    return first ? x0 : x1;
}

__device__ float jax_gumbel(uint32_t key_lo, uint32_t flat) {
    uint32_t bits = jax_random_bits(key_lo, flat);
    uint32_t v = (bits >> 9) | 0x3F800000u;
    float u = __uint_as_float(v) - 1.0f;
    u = u + 1e-10f;
    u = fmaxf(1e-10f, u);
    return -logf(-logf(u));
}

__device__ __forceinline__ uint32_t f2bf(float f) {   // RNE f32->bf16 bits
    uint32_t u = __float_as_uint(f);
    return (u + 0x7FFFu + ((u >> 16) & 1u)) >> 16;
}

// ---------------- fused obs-proj + LSTM cell ----------------
// grid (32, 8): 8 rows, 32 hid-cols (=128 gate-cols) per block
// block (0,0) also zeroes the ci/cj atomic accumulators for this call
__global__ __launch_bounds__(256) void k_lstm(
        const float* __restrict__ obs, const float* __restrict__ hs,
        const float* __restrict__ cs,
        const float* __restrict__ w_obs, const float* __restrict__ b_obs,
        const float* __restrict__ w_ih, const float* __restrict__ b_ih,
        const float* __restrict__ w_hh, const float* __restrict__ b_hh,
        float* __restrict__ h_out, float* __restrict__ c_out,
        float* __restrict__ ci1, float* __restrict__ cj1,
        float* __restrict__ ci2, float* __restrict__ cj2) {
    __shared__ float o_l[8][128];
    __shared__ float h_l[8][256];
    __shared__ float x_l[8][256];
    __shared__ float red[8192];            // 32KB, reused by both phases
    int r0 = blockIdx.x * 8, c0 = blockIdx.y * 32, t = threadIdx.x;
    if (blockIdx.x == 0 && blockIdx.y == 0) {
        for (int idx = t; idx < 1024; idx += 256) { ci1[idx] = 0.f; cj1[idx] = 0.f; }
        ci2[t] = 0.f; cj2[t] = 0.f;
    }
    ((f32x4*)o_l)[t] = ((const f32x4*)(obs + r0 * 128))[t];
    ((f32x4*)h_l)[t] = ((const f32x4*)(hs + r0 * 256))[t];
    ((f32x4*)h_l)[t + 256] = ((const f32x4*)(hs + r0 * 256))[t + 256];
    __syncthreads();
    {   // obs proj
        int ks = t >> 6, q = t & 63;
        f32x4 acc[8];
#pragma unroll
        for (int r = 0; r < 8; ++r) acc[r] = (f32x4){0.f, 0.f, 0.f, 0.f};
#pragma unroll
        for (int k = ks * 32; k < ks * 32 + 32; ++k) {
            f32x4 w = *(const f32x4*)(w_obs + k * 256 + q * 4);
#pragma unroll
            for (int r = 0; r < 8; ++r) {
                float xv = o_l[r][k];
                acc[r].x += xv * w.x; acc[r].y += xv * w.y;
                acc[r].z += xv * w.z; acc[r].w += xv * w.w;
            }
        }
#pragma unroll
        for (int r = 0; r < 8; ++r)
            *(f32x4*)&red[(ks * 8 + r) * 256 + q * 4] = acc[r];
    }
    __syncthreads();
#pragma unroll
    for (int rep = 0; rep < 8; ++rep) {
        int o = t + rep * 256;
        int r = o >> 8, c = o & 255;
        float s = b_obs[c];
#pragma unroll
        for (int k2 = 0; k2 < 4; ++k2) s += red[(k2 * 8 + r) * 256 + c];
        x_l[r][c] = s;
    }
    __syncthreads();
    {   // gates
        int ks = t >> 5, cg = t & 31;
        int g = cg >> 3, qd = cg & 7;
        int col = g * 256 + c0 + qd * 4;
        const float* W = (ks < 4) ? w_ih : w_hh;
        const float* xl = (ks < 4) ? &x_l[0][0] : &h_l[0][0];
        int kb = (ks & 3) * 64;
        f32x4 acc[8];
#pragma unroll
        for (int r = 0; r < 8; ++r) acc[r] = (f32x4){0.f, 0.f, 0.f, 0.f};
#pragma unroll
        for (int kk = 0; kk < 64; ++kk) {
            int k = kb + kk;
            f32x4 w = *(const f32x4*)(W + k * 1024 + col);
#pragma unroll
            for (int r = 0; r < 8; ++r) {
                float xv = xl[r * 256 + k];
                acc[r].x += xv * w.x; acc[r].y += xv * w.y;
                acc[r].z += xv * w.z; acc[r].w += xv * w.w;
            }
        }
        __syncthreads();
#pragma unroll
        for (int r = 0; r < 8; ++r)
            *(f32x4*)&red[(ks * 8 + r) * 128 + cg * 4] = acc[r];
    }
    __syncthreads();
    {
        int r = t >> 5, hc = t & 31;
        int gc = c0 + hc;
        float gate[4];
#pragma unroll
        for (int g = 0; g < 4; ++g) {
            float s = b_ih[g * 256 + gc] + b_hh[g * 256 + gc];
#pragma unroll
            for (int ks = 0; ks < 8; ++ks) s += red[(ks * 8 + r) * 128 + g * 32 + hc];
            gate[g] = s;
        }
        float ig = 1.f / (1.f + expf(-gate[0]));
        float fg = 1.f / (1.f + expf(-gate[1]));
        float gg = tanhf(gate[2]);
        float og = 1.f / (1.f + expf(-gate[3]));
        float cn = fg * cs[(r0 + r) * 256 + gc] + ig * gg;
        float hn = og * tanhf(cn);
        h_out[(r0 + r) * 256 + gc] = hn;
        c_out[(r0 + r) * 256 + gc] = cn;
    }
}

// ---------------- generic R-row x 64-col GEMM tile ----------------
template<int K, int R>
__device__ __forceinline__ void gemm_core(const float* __restrict__ X, int xs, int r0,
                                          const float* __restrict__ W, int ws,
                                          const float* __restrict__ bias,
                                          float* __restrict__ Y, int ys, int t,
                                          float* xr, float* red) {
    constexpr int KQ = K / 4;
#pragma unroll
    for (int q = t; q < R * KQ; q += 256) {
        int r = q / KQ, c = q % KQ;
        ((f32x4*)xr)[r * KQ + c] = ((const f32x4*)(X + (r0 + r) * xs))[c];
    }
    __syncthreads();
    constexpr int KP = K / 16;
    int qd = t & 15, ks = t >> 4;
    f32x4 acc[R];
#pragma unroll
    for (int r = 0; r < R; ++r) acc[r] = (f32x4){0.f, 0.f, 0.f, 0.f};
#pragma unroll
    for (int k = ks * KP; k < ks * KP + KP; ++k) {
        f32x4 w = *(const f32x4*)(W + k * ws + qd * 4);
#pragma unroll
        for (int r = 0; r < R; ++r) {
            float xv = xr[r * K + k];
            acc[r].x += xv * w.x; acc[r].y += xv * w.y;
            acc[r].z += xv * w.z; acc[r].w += xv * w.w;
        }
    }
#pragma unroll
    for (int r = 0; r < R; ++r)
        *(f32x4*)&red[(ks * R + r) * 64 + qd * 4] = acc[r];
    __syncthreads();
#pragma unroll
    for (int rep = 0; rep < (R * 64 + 255) / 256; ++rep) {
        int o = t + rep * 256;
        int r = o >> 6, c = o & 63;
        float s = bias ? bias[c] : 0.f;
#pragma unroll
        for (int ks2 = 0; ks2 < 16; ++ks2) s += red[(ks2 * R + r) * 64 + c];
        Y[(r0 + r) * ys + c] = s;
    }
}

// comm = h_new @ w_me + b_me; grid (64, 4): 4-row tiles, full CU coverage
__global__ __launch_bounds__(256) void k_comm(const float* __restrict__ X,
                                              const float* __restrict__ W,
                                              const float* __restrict__ bias,
                                              float* __restrict__ Y) {
    __shared__ float xr[4 * 256];
    __shared__ float red[16 * 4 * 64];
    int cb = blockIdx.y * 64;
    gemm_core<256, 4>(X, 256, blockIdx.x * 4, W + cb, 256, bias + cb,
                      Y + cb, 256, threadIdx.x, xr, red);
}

// multi-target GEMM from comm, with fused GAT1 att-coef partials (atomics).
// grid (32, 16): y<8 -> h1 slices (+ci1/cj1); y>=8 -> A1,B1,A2,B2 halves
__global__ __launch_bounds__(256) void k_mgemm(const float* __restrict__ comm,
        const float* __restrict__ g1_w, const float* __restrict__ g1ai,
        const float* __restrict__ g1aj,
        const float* __restrict__ s1w1, const float* __restrict__ s1b1,
        const float* __restrict__ s2w1, const float* __restrict__ s2b1,
        float* __restrict__ h1, float* __restrict__ A1, float* __restrict__ B1,
        float* __restrict__ A2, float* __restrict__ B2,
        float* __restrict__ ci1, float* __restrict__ cj1) {
    __shared__ float xr[8 * 256];
    __shared__ float red[16 * 8 * 64];
    int y = blockIdx.y, t = threadIdx.x, r0 = blockIdx.x * 8;
    const float* W; int ws; const float* bias; float* Y; int ys;
    if (y < 8) {
        W = g1_w + y * 64; ws = 512; bias = nullptr; Y = h1 + y * 64; ys = 512;
    } else {
        int idx = y - 8;
        int sel = idx >> 2, part = (idx >> 1) & 1, half = idx & 1;
        W = (sel ? s2w1 : s1w1) + part * (256 * 128) + half * 64; ws = 128;
        bias = part ? nullptr : ((sel ? s2b1 : s1b1) + half * 64);
        float* tgt = sel ? (part ? B2 : A2) : (part ? B1 : A1);
        Y = tgt + half * 64; ys = 128;
    }
    // gemm body (K=256, 8 rows)
#pragma unroll
    for (int q = t; q < 512; q += 256) {
        int r = q >> 6, c = q & 63;
        ((f32x4*)xr)[r * 64 + c] = ((const f32x4*)(comm + (r0 + r) * 256))[c];
    }
    __syncthreads();
    int qd = t & 15, ks = t >> 4;
    f32x4 acc[8];
#pragma unroll
    for (int r = 0; r < 8; ++r) acc[r] = (f32x4){0.f, 0.f, 0.f, 0.f};
#pragma unroll
    for (int k = ks * 16; k < ks * 16 + 16; ++k) {
        f32x4 w = *(const f32x4*)(W + k * ws + qd * 4);
#pragma unroll
        for (int r = 0; r < 8; ++r) {
            float xv = xr[r * 256 + k];
            acc[r].x += xv * w.x; acc[r].y += xv * w.y;
            acc[r].z += xv * w.z; acc[r].w += xv * w.w;
        }
    }
#pragma unroll
    for (int r = 0; r < 8; ++r)
        *(f32x4*)&red[(ks * 8 + r) * 64 + qd * 4] = acc[r];
    __syncthreads();
#pragma unroll
    for (int rep = 0; rep < 2; ++rep) {
        int o = t + rep * 256;
        int r = o >> 6, c = o & 63;     // wave-uniform row; c == lane
        float s = bias ? bias[c] : 0.f;
#pragma unroll
        for (int ks2 = 0; ks2 < 16; ++ks2) s += red[(ks2 * 8 + r) * 64 + c];
        Y[(r0 + r) * ys + c] = s;
        if (y < 8) {                    // fused attc1 partial for this 64-col slice
            int h = y >> 1;
            int f = ((y & 1) << 6) + c;
            float pi = s * g1ai[h * 128 + f];
            float pj = s * g1aj[h * 128 + f];
#pragma unroll
            for (int off = 32; off; off >>= 1) {
                pi += __shfl_xor(pi, off);
                pj += __shfl_xor(pj, off);
            }
            if ((t & 63) == 0) {
                atomicAdd(&ci1[(r0 + r) * 4 + h], pi);
                atomicAdd(&cj1[(r0 + r) * 4 + h], pj);
            }
        }
    }
}

// ---------------- scheduler: z1(bf16,LDS) -> MFMA z2 -> logits -> gumbel argmax ----------------
// grid (256, 2): block = (agent i, scheduler s)
__global__ __launch_bounds__(256) void k_sched(
        const float* __restrict__ A1, const float* __restrict__ B1,
        const float* __restrict__ s1w2, const float* __restrict__ s1b2,
        const float* __restrict__ s1w3, const float* __restrict__ s1b3,
        const float* __restrict__ A2, const float* __restrict__ B2,
        const float* __restrict__ s2w2, const float* __restrict__ s2b2,
        const float* __restrict__ s2w3, const float* __restrict__ s2b3,
        float* __restrict__ adj1, float* __restrict__ adj2) {
    __shared__ __align__(16) char z1z2[65536];   // z1 bf16 [256][128] swz | z2 f32 [256][36]
    __shared__ __align__(16) char w2l[8192];     // w2^T bf16 [32][128] swz
    __shared__ float a_l[128];
    __shared__ float b2_l[32], w3_l[64], b3_l[2];
    int i = blockIdx.x, t = threadIdx.x, s = blockIdx.y;
    const float* A  = s ? A2 : A1;
    const float* B  = s ? B2 : B1;
    const float* w2 = s ? s2w2 : s1w2;
    const float* b2 = s ? s2b2 : s1b2;
    const float* w3 = s ? s2w3 : s1w3;
    const float* b3 = s ? s2b3 : s1b3;
    float* adj = s ? adj2 : adj1;
    uint32_t key_lo = (uint32_t)(s + 1);

    if (t < 32) ((f32x4*)a_l)[t] = ((const f32x4*)(A + i * 128))[t];
    if (t < 32) b2_l[t] = b2[t];
    if (t < 64) w3_l[t] = w3[t];
    if (t < 2)  b3_l[t] = b3[t];
    {   // w2 [128][32] -> bf16 transposed [c][k], swizzled
        int c = t & 31, kq = t >> 5;
        uint32_t* dst = (uint32_t*)w2l;
#pragma unroll
        for (int e = 0; e < 8; ++e) {
            int k = kq * 16 + e * 2;
            uint32_t word = f2bf(w2[k * 32 + c]) | (f2bf(w2[(k + 1) * 32 + c]) << 16);
            int byte = (c * 256 + k * 2) ^ ((c & 7) << 4);
            dst[byte >> 2] = word;
        }
    }
    __syncthreads();
    // z1 = relu(A[i] + B[j]) -> bf16 LDS, swizzled rows
#pragma unroll
    for (int rep = 0; rep < 4; ++rep) {
        int j = (t >> 2) + rep * 64;
        int kq = t & 3;
        const f32x4* bp = (const f32x4*)(B + j * 128 + kq * 32);
        uint32_t words[16];
#pragma unroll
        for (int q = 0; q < 8; ++q) {
            f32x4 bv = bp[q];
            int k = kq * 32 + q * 4;
            float z0 = fmaxf(a_l[k] + bv.x, 0.f);
            float z1v = fmaxf(a_l[k + 1] + bv.y, 0.f);
            float z2v = fmaxf(a_l[k + 2] + bv.z, 0.f);
            float z3v = fmaxf(a_l[k + 3] + bv.w, 0.f);
            words[q * 2]     = f2bf(z0) | (f2bf(z1v) << 16);
            words[q * 2 + 1] = f2bf(z2v) | (f2bf(z3v) << 16);
        }
#pragma unroll
        for (int w4 = 0; w4 < 4; ++w4) {
            int byte = (j * 256 + kq * 64 + w4 * 16) ^ ((j & 7) << 4);
            *(uint4*)(z1z2 + byte) = make_uint4(words[w4 * 4], words[w4 * 4 + 1],
                                                words[w4 * 4 + 2], words[w4 * 4 + 3]);
        }
    }
    __syncthreads();
    // MFMA: z2[256 j][32 c] = z1 @ w2
    int w = t >> 6, l = t & 63;
    bfrag bf[2][4];
#pragma unroll
    for (int ct = 0; ct < 2; ++ct)
#pragma unroll
        for (int ks = 0; ks < 4; ++ks) {
            int col = ct * 16 + (l & 15);
            int k = ks * 32 + (l >> 4) * 8;
            int byte = (col * 256 + k * 2) ^ ((col & 7) << 4);
            bf[ct][ks] = *(bfrag*)(w2l + byte);
        }
    cfrag acc[4][2];
    cfrag zz = {0.f, 0.f, 0.f, 0.f};
#pragma unroll
    for (int rt = 0; rt < 4; ++rt) { acc[rt][0] = zz; acc[rt][1] = zz; }
#pragma unroll
    for (int rt = 0; rt < 4; ++rt) {
        int j = (w * 4 + rt) * 16 + (l & 15);
#pragma unroll
        for (int ks = 0; ks < 4; ++ks) {
            int byte = (j * 256 + (ks * 32 + (l >> 4) * 8) * 2) ^ ((j & 7) << 4);
            bfrag af = *(bfrag*)(z1z2 + byte);
            acc[rt][0] = __builtin_amdgcn_mfma_f32_16x16x32_bf16(af, bf[0][ks], acc[rt][0], 0, 0, 0);
            acc[rt][1] = __builtin_amdgcn_mfma_f32_16x16x32_bf16(af, bf[1][ks], acc[rt][1], 0, 0, 0);
        }
    }
    __syncthreads();
    float* z2 = (float*)z1z2;                    // [256][36] padded
#pragma unroll
    for (int rt = 0; rt < 4; ++rt)
#pragma unroll
        for (int ct = 0; ct < 2; ++ct)
#pragma unroll
            for (int r = 0; r < 4; ++r) {
                int j = (w * 4 + rt) * 16 + (l >> 4) * 4 + r;
                int c = ct * 16 + (l & 15);
                z2[j * 36 + c] = acc[rt][ct][r];
            }
    __syncthreads();
    {   // epilogue: one j per thread
        int j = t;
        float p0 = 0.f, p1 = 0.f;
#pragma unroll
        for (int c = 0; c < 32; ++c) {
            float zv = fmaxf(z2[j * 36 + c] + b2_l[c], 0.f);
            p0 += zv * w3_l[2 * c];
            p1 += zv * w3_l[2 * c + 1];
        }
        float l0 = p0 + b3_l[0], l1 = p1 + b3_l[1];
        uint32_t flat = (uint32_t)(i * 256 + j) * 2u;
        float g0 = jax_gumbel(key_lo, flat);
        float g1 = jax_gumbel(key_lo, flat + 1u);
        adj[i * 256 + j] = (l1 + g1 > l0 + g0) ? 1.0f : 0.0f;
    }
}

// ---------------- GAT1: grid (128, 2) — 2 rows, 256-col slice ----------------
__global__ __launch_bounds__(256) void k_gat1(const float* __restrict__ H,
        const float* __restrict__ adj, const float* __restrict__ ci,
        const float* __restrict__ cj, const float* __restrict__ bias,
        float* __restrict__ out) {
    __shared__ float att[2][4][256];
    __shared__ float red[4][2][256];
    int i0 = blockIdx.x * 2, cb = blockIdx.y * 256, t = threadIdx.x;
#pragma unroll
    for (int r = 0; r < 2; ++r) {
        int i = i0 + r;
        float adjv = (t == i) ? 1.f : adj[i * 256 + t];
#pragma unroll
        for (int h = 0; h < 4; ++h) {
            float e = ci[i * 4 + h] + cj[t * 4 + h];
            e = e >= 0.f ? e : 0.2f * e;
            att[r][h][t] = adjv > 0.f ? e : -INFINITY;
        }
    }
    __syncthreads();
    {
        int wv = t >> 6, lane = t & 63;
        for (int p = wv; p < 8; p += 4) {
            int r = p >> 2, h = p & 3;
            float* ar = att[r][h];
            float m = -INFINITY;
            for (int j = lane; j < 256; j += 64) m = fmaxf(m, ar[j]);
            for (int off = 32; off; off >>= 1) m = fmaxf(m, __shfl_xor(m, off));
            float vals[4], sm = 0.f;
#pragma unroll
            for (int q = 0; q < 4; ++q) {
                float v = expf(ar[lane + 64 * q] - m);
                vals[q] = v; sm += v;
            }
            for (int off = 32; off; off >>= 1) sm += __shfl_xor(sm, off);
            float inv = 1.f / sm;
#pragma unroll
            for (int q = 0; q < 4; ++q) ar[lane + 64 * q] = vals[q] * inv;
        }
    }
    __syncthreads();
    {
        int q = t & 63, js = t >> 6;
        int c = cb + q * 4;
        int h = c >> 7;
        f32x4 a0 = {0.f, 0.f, 0.f, 0.f}, a1 = a0;
        const float* ar0 = att[0][h];
        const float* ar1 = att[1][h];
#pragma unroll
        for (int j = js * 64; j < js * 64 + 64; ++j) {
            f32x4 hv = *(const f32x4*)(H + j * 512 + c);
            float v0 = ar0[j], v1 = ar1[j];
            a0.x += v0 * hv.x; a0.y += v0 * hv.y; a0.z += v0 * hv.z; a0.w += v0 * hv.w;
            a1.x += v1 * hv.x; a1.y += v1 * hv.y; a1.z += v1 * hv.z; a1.w += v1 * hv.w;
        }
        *(f32x4*)&red[js][0][q * 4] = a0;
        *(f32x4*)&red[js][1][q * 4] = a1;
    }
    __syncthreads();
#pragma unroll
    for (int rep = 0; rep < 2; ++rep) {
        int o = t + rep * 256;
        int r = o >> 8, c = o & 255;
        float s = red[0][r][c] + red[1][r][c] + red[2][r][c] + red[3][r][c] + bias[cb + c];
        out[(i0 + r) * 512 + cb + c] = s > 0.f ? s : expm1f(s);
    }
}

// ---------------- h2 = comm2 @ g2_w, fused GAT2 att-coef partials ----------------
// grid (64, 4): 4-row tiles, full CU coverage
__global__ __launch_bounds__(256) void k_g2gemm(const float* __restrict__ comm2,
        const float* __restrict__ g2w, const float* __restrict__ g2ai,
        const float* __restrict__ g2aj, float* __restrict__ h2,
        float* __restrict__ ci2, float* __restrict__ cj2) {
    __shared__ float xr[4 * 512];
    __shared__ float red[16 * 4 * 64];
    int t = threadIdx.x, r0 = blockIdx.x * 4, cb = blockIdx.y * 64;
    const float* W = g2w + cb;
#pragma unroll
    for (int q = t; q < 512; q += 256) {
        int r = q >> 7, c = q & 127;
        ((f32x4*)xr)[r * 128 + c] = ((const f32x4*)(comm2 + (r0 + r) * 512))[c];
    }
    __syncthreads();
    int qd = t & 15, ks = t >> 4;
    f32x4 acc[4];
#pragma unroll
    for (int r = 0; r < 4; ++r) acc[r] = (f32x4){0.f, 0.f, 0.f, 0.f};
#pragma unroll
    for (int k = ks * 32; k < ks * 32 + 32; ++k) {
        f32x4 w = *(const f32x4*)(W + k * 256 + qd * 4);
#pragma unroll
        for (int r = 0; r < 4; ++r) {
            float xv = xr[r * 512 + k];
            acc[r].x += xv * w.x; acc[r].y += xv * w.y;
            acc[r].z += xv * w.z; acc[r].w += xv * w.w;
        }
    }
#pragma unroll
    for (int r = 0; r < 4; ++r)
        *(f32x4*)&red[(ks * 4 + r) * 64 + qd * 4] = acc[r];
    __syncthreads();
    {
        int o = t;
        int r = o >> 6, c = o & 63;     // wave-uniform row; c == lane
        float s = 0.f;
#pragma unroll
        for (int ks2 = 0; ks2 < 16; ++ks2) s += red[(ks2 * 4 + r) * 64 + c];
        h2[(r0 + r) * 256 + cb + c] = s;
        // fused attc2 partial
        float pi = s * g2ai[cb + c];
        float pj = s * g2aj[cb + c];
#pragma unroll
        for (int off = 32; off; off >>= 1) {
            pi += __shfl_xor(pi, off);
            pj += __shfl_xor(pj, off);
        }
        if ((t & 63) == 0) {
            atomicAdd(&ci2[r0 + r], pi);
            atomicAdd(&cj2[r0 + r], pj);
        }
    }
}

// ---------------- final: GAT2 + message-decode + value/action heads ----------------
__global__ __launch_bounds__(256) void k_final(const float* __restrict__ H,
        const float* __restrict__ adj, const float* __restrict__ ci,
        const float* __restrict__ cj, const float* __restrict__ g2_b,
        const float* __restrict__ w_md, const float* __restrict__ b_md,
        const float* __restrict__ h_new,
        const float* __restrict__ w_v, const float* __restrict__ b_v,
        const float* __restrict__ w_a, const float* __restrict__ b_a,
        float* __restrict__ value, float* __restrict__ action) {
    __shared__ float att[256];
    __shared__ float buf[4][256];
    __shared__ float out2[256];
    __shared__ float comm3[256];
    __shared__ float hrow[256];
    __shared__ float hred[4][16];
    __shared__ float vred[4];
    int i = blockIdx.x, t = threadIdx.x;
    hrow[t] = h_new[i * 256 + t];
    {
        float adjv = (t == i) ? 1.f : adj[i * 256 + t];
        float e = ci[i] + cj[t];
        e = e >= 0.f ? e : 0.2f * e;
        att[t] = adjv > 0.f ? e : -INFINITY;
    }
    __syncthreads();
    {
        int lane = t & 63;
        float m = -INFINITY;
        for (int j = lane; j < 256; j += 64) m = fmaxf(m, att[j]);
        for (int off = 32; off; off >>= 1) m = fmaxf(m, __shfl_xor(m, off));
        float sm = 0.f;
        for (int j = lane; j < 256; j += 64) sm += expf(att[j] - m);
        for (int off = 32; off; off >>= 1) sm += __shfl_xor(sm, off);
        float inv = 1.f / sm;
        float myval = expf(att[t] - m) * inv;
        __syncthreads();
        att[t] = myval;
    }
    __syncthreads();
    {   // out2 = att @ H (+ g2_b)
        int q = t & 63, js = t >> 6;
        f32x4 acc = {0.f, 0.f, 0.f, 0.f};
#pragma unroll
        for (int j = js * 64; j < js * 64 + 64; ++j) {
            f32x4 hv = *(const f32x4*)(H + j * 256 + q * 4);
            float av = att[j];
            acc.x += av * hv.x; acc.y += av * hv.y; acc.z += av * hv.z; acc.w += av * hv.w;
        }
        *(f32x4*)&buf[js][q * 4] = acc;
    }
    __syncthreads();
    out2[t] = buf[0][t] + buf[1][t] + buf[2][t] + buf[3][t] + g2_b[t];
    __syncthreads();
    {   // comm3 = out2 @ w_md + b_md
        int q = t & 63, ks = t >> 6;
        f32x4 acc = {0.f, 0.f, 0.f, 0.f};
#pragma unroll
        for (int k = ks * 64; k < ks * 64 + 64; ++k) {
            f32x4 wv = *(const f32x4*)(w_md + k * 256 + q * 4);
            float xv = out2[k];
            acc.x += xv * wv.x; acc.y += xv * wv.y; acc.z += xv * wv.z; acc.w += xv * wv.w;
        }
        *(f32x4*)&buf[ks][q * 4] = acc;
    }
    __syncthreads();
    comm3[t] = buf[0][t] + buf[1][t] + buf[2][t] + buf[3][t] + b_md[t];
    __syncthreads();
    int w = t >> 6, l = t & 63;
    {   // value
        float p = hrow[t] * w_v[t] + comm3[t] * w_v[256 + t];
        for (int off = 32; off; off >>= 1) p += __shfl_xor(p, off);
        if (l == 0) vred[w] = p;
    }
    {   // action: o = l&15 (10 used), kseg = w*4 + (l>>4)
        int o = l & 15;
        int kseg = w * 4 + (l >> 4);
        float acc = 0.f;
        if (o < 10) {
#pragma unroll
            for (int kk = 0; kk < 32; ++kk) {
                int k = kseg * 32 + kk;
                float x = (kseg < 8) ? hrow[k] : comm3[k - 256];
                acc += x * w_a[k * 10 + o];
            }
        }
        acc += __shfl_xor(acc, 16);
        acc += __shfl_xor(acc, 32);
        if (l < 16) hred[w][l] = acc;
    }
    __syncthreads();
    if (t < 16) {
        int o = t;
        float logit = (o < 10)
            ? hred[0][o] + hred[1][o] + hred[2][o] + hred[3][o] + b_a[o]
            : -INFINITY;
        float m = logit;
        for (int off = 8; off; off >>= 1) m = fmaxf(m, __shfl_xor(m, off));
        float ex = (o < 10) ? expf(logit - m) : 0.f;
        float sm = ex;
        for (int off = 8; off; off >>= 1) sm += __shfl_xor(sm, off);
        if (o < 10) action[i * 10 + o] = logit - m - logf(sm);
        if (o == 0) value[i] = vred[0] + vred[1] + vred[2] + vred[3] + b_v[0];
    }
}

extern "C" void kernel_launch(void* const* d_in, const int* in_sizes, int n_in,
                              void* d_out, int out_size, void* d_ws, size_t ws_size,
                              hipStream_t stream) {
    const float* obs   = (const float*)d_in[0];
    const float* hs    = (const float*)d_in[1];
    const float* cs    = (const float*)d_in[2];
    const float* w_obs = (const float*)d_in[3];
    const float* b_obs = (const float*)d_in[4];
    const float* w_ih  = (const float*)d_in[5];
    const float* b_ih  = (const float*)d_in[6];
    const float* w_hh  = (const float*)d_in[7];
    const float* b_hh  = (const float*)d_in[8];
    const float* w_me  = (const float*)d_in[9];
    const float* b_me  = (const float*)d_in[10];
    const float* w_md  = (const float*)d_in[11];
    const float* b_md  = (const float*)d_in[12];
    const float* s1_w1 = (const float*)d_in[13];
    const float* s1_b1 = (const float*)d_in[14];
    const float* s1_w2 = (const float*)d_in[15];
    const float* s1_b2 = (const float*)d_in[16];
    const float* s1_w3 = (const float*)d_in[17];
    const float* s1_b3 = (const float*)d_in[18];
    const float* s2_w1 = (const float*)d_in[19];
    const float* s2_b1 = (const float*)d_in[20];
    const float* s2_w2 = (const float*)d_in[21];
    const float* s2_b2 = (const float*)d_in[22];
    const float* s2_w3 = (const float*)d_in[23];
    const float* s2_b3 = (const float*)d_in[24];
    const float* g1_w  = (const float*)d_in[25];
    const float* g1_ai = (const float*)d_in[26];
    const float* g1_aj = (const float*)d_in[27];
    const float* g1_b  = (const float*)d_in[28];
    const float* g2_w  = (const float*)d_in[29];
    const float* g2_ai = (const float*)d_in[30];
    const float* g2_aj = (const float*)d_in[31];
    const float* g2_b  = (const float*)d_in[32];
    const float* w_v   = (const float*)d_in[33];
    const float* b_v   = (const float*)d_in[34];
    const float* w_a   = (const float*)d_in[35];
    const float* b_a   = (const float*)d_in[36];

    float* out = (float*)d_out;
    float* action = out;               // [1,256,10] = 2560
    float* value  = out + 2560;        // [256,1]
    float* h_new  = out + 2816;        // [256,256]
    float* c_new  = out + 68352;       // [256,256]

    float* ws = (float*)d_ws;
    float* comm  = ws;                 // 65536
    float* A1    = ws + 65536;         // 32768
    float* B1    = ws + 98304;         // 32768
    float* A2    = ws + 131072;        // 32768
    float* B2    = ws + 163840;        // 32768
    float* adj1  = ws + 196608;        // 65536
    float* adj2  = ws + 262144;        // 65536
    float* h1    = ws + 327680;        // 131072
    float* ci1   = ws + 458752;        // 1024
    float* cj1   = ws + 459776;        // 1024
    float* comm2 = ws + 460800;        // 131072
    float* h2    = ws + 591872;        // 65536
    float* ci2   = ws + 657408;        // 256
    float* cj2   = ws + 657664;        // 256

    k_lstm<<<dim3(32, 8), 256, 0, stream>>>(obs, hs, cs, w_obs, b_obs,
                                            w_ih, b_ih, w_hh, b_hh, h_new, c_new,
                                            ci1, cj1, ci2, cj2);
    k_comm<<<dim3(64, 4), 256, 0, stream>>>(h_new, w_me, b_me, comm);
    k_mgemm<<<dim3(32, 16), 256, 0, stream>>>(comm, g1_w, g1_ai, g1_aj,
                                              s1_w1, s1_b1, s2_w1, s2_b1,
                                              h1, A1, B1, A2, B2, ci1, cj1);
    k_sched<<<dim3(256, 2), 256, 0, stream>>>(A1, B1, s1_w2, s1_b2, s1_w3, s1_b3,
                                              A2, B2, s2_w2, s2_b2, s2_w3, s2_b3,
                                              adj1, adj2);
    k_gat1<<<dim3(128, 2), 256, 0, stream>>>(h1, adj1, ci1, cj1, g1_b, comm2);
    k_g2gemm<<<dim3(64, 4), 256, 0, stream>>>(comm2, g2_w, g2_ai, g2_aj, h2, ci2, cj2);
    k_final<<<NA, 256, 0, stream>>>(h2, adj2, ci2, cj2, g2_b, w_md, b_md, h_new,
                                    w_v, b_v, w_a, b_a, value, action);
}